// Round 14
// baseline (323.294 us; speedup 1.0000x reference)
//
#include <hip/hip_runtime.h>
#include <hip/hip_bf16.h>

#define B_ 16
#define N_ 1024
#define C_ 256
#define R_ 8
#define E_ 262144
#define NS_ 32
#define BN_ (B_*N_)
#define BNC_ (BN_*C_)

typedef __hip_bfloat16 bf16;
typedef __attribute__((ext_vector_type(4))) float f32x4;
typedef __attribute__((ext_vector_type(8))) short bf16x8;

__device__ __forceinline__ float b2f(bf16 x) { return __bfloat162float(x); }
__device__ __forceinline__ bf16  f2b(float x) { return __float2bfloat16(x); }
__device__ __forceinline__ float us2f(unsigned short u) { return __uint_as_float((unsigned)u << 16); }

// async global->LDS, 16B per lane (wave-uniform LDS base + lane*16 implicit)
__device__ __forceinline__ void gload16(const void* g, void* l) {
    auto gp = (const __attribute__((address_space(1))) void*)(unsigned long long)g;
    auto lp = (__attribute__((address_space(3))) void*)(unsigned)(unsigned long long)l;
    __builtin_amdgcn_global_load_lds(gp, lp, 16, 0, 0);
}

// ---------------- bf16 MFMA GEMM (128x128 tile): C = act(A @ B^T + bias) ----------------
// Depth-3 pipeline (48 KB LDS), vmcnt ladder 8/4/0; XOR slot swizzle both sides;
// XCD-aware block swizzle (bijective when nwg % 8 == 0).
template<int ACT>
__global__ __launch_bounds__(256) void gemm_bf16(
    const bf16* __restrict__ A, int lda, long long sA,
    const bf16* __restrict__ Bm, int ldb, long long sB,
    bf16* __restrict__ Cc, int ldc, long long sC,
    const float* __restrict__ bias, const float* __restrict__ bias2,
    const float* __restrict__ bias3, int K)
{
    __shared__ short sbuf[24576];        // 48 KB
    const int tid = threadIdx.x;
    const int lane = tid & 63, w = tid >> 6;
    const int wr = w >> 1, wc = w & 1;

    const int gx = gridDim.x;
    const int nwg = gx * gridDim.y;
    int id = blockIdx.y * gx + blockIdx.x;
    if ((nwg & 7) == 0) { const int cpx = nwg >> 3; id = (id & 7) * cpx + (id >> 3); }
    const int bm = (id / gx) * 128, bn = (id % gx) * 128;

    const bf16* Ab = A + (size_t)blockIdx.z * sA;
    const bf16* Bb = Bm + (size_t)blockIdx.z * sB;
    bf16* Cb = Cc + (size_t)blockIdx.z * sC;

    const int rg = lane >> 2;
    const int kswz = ((lane & 3) ^ ((rg >> 1) & 3)) * 8;

    f32x4 acc[4][4];
    const f32x4 zz = {0.f, 0.f, 0.f, 0.f};
    #pragma unroll
    for (int i = 0; i < 4; ++i)
        #pragma unroll
        for (int j = 0; j < 4; ++j) acc[i][j] = zz;

    const int fr = lane & 15;
    const int fm = lane >> 4;
    const int fslot = (fm ^ ((fr >> 1) & 3)) * 8;

    const int NI = K >> 5;

#define STAGE_AB(bi, kk) do {                                                          \
    _Pragma("unroll")                                                                  \
    for (int t_ = 0; t_ < 2; ++t_) {                                                   \
        gload16(Ab + (size_t)(bm + t_*64 + w*16 + rg) * lda + (kk) + kswz,             \
                sbuf + (bi)*4096 + t_*2048 + w*512);                                   \
        gload16(Bb + (size_t)(bn + t_*64 + w*16 + rg) * ldb + (kk) + kswz,             \
                sbuf + 12288 + (bi)*4096 + t_*2048 + w*512);                           \
    } } while (0)

    STAGE_AB(0, 0);
    if (NI > 1) STAGE_AB(1, 32);
    if (NI > 2) STAGE_AB(2, 64);

    int cur = 0;
    for (int i = 0; i < NI; ++i) {
        if (i + 2 < NI)      asm volatile("s_waitcnt vmcnt(8)" ::: "memory");
        else if (i + 1 < NI) asm volatile("s_waitcnt vmcnt(4)" ::: "memory");
        else                 asm volatile("s_waitcnt vmcnt(0)" ::: "memory");
        __builtin_amdgcn_s_barrier();
        __builtin_amdgcn_sched_barrier(0);

        bf16x8 af[4], bfr[4];
        const short* Ac = sbuf + cur * 4096;
        const short* Bc = sbuf + 12288 + cur * 4096;
        #pragma unroll
        for (int ii = 0; ii < 4; ++ii)
            af[ii] = *(const bf16x8*)&Ac[(wr*64 + ii*16 + fr)*32 + fslot];
        #pragma unroll
        for (int jj = 0; jj < 4; ++jj)
            bfr[jj] = *(const bf16x8*)&Bc[(wc*64 + jj*16 + fr)*32 + fslot];

        asm volatile("s_waitcnt lgkmcnt(0)" ::: "memory");
        __builtin_amdgcn_s_barrier();
        __builtin_amdgcn_sched_barrier(0);
        if (i + 3 < NI) STAGE_AB(cur, (i + 3) * 32);

        #pragma unroll
        for (int ii = 0; ii < 4; ++ii)
            #pragma unroll
            for (int jj = 0; jj < 4; ++jj)
                acc[ii][jj] = __builtin_amdgcn_mfma_f32_16x16x32_bf16(af[ii], bfr[jj], acc[ii][jj], 0, 0, 0);
        cur = (cur == 2) ? 0 : cur + 1;
    }
#undef STAGE_AB

    __syncthreads();
    const int er = (lane >> 4) * 4, ec = lane & 15;
    #pragma unroll
    for (int half = 0; half < 2; ++half) {
        if (wr == half) {
            #pragma unroll
            for (int j = 0; j < 4; ++j) {
                const int col = bn + wc*64 + j*16 + ec;
                float bvv = 0.0f;
                if (bias) {
                    const int seg = col >> 8;
                    const float* bp = (seg == 0) ? bias : (seg == 1 ? bias2 : bias3);
                    bvv = bp[col & 255];
                }
                #pragma unroll
                for (int i = 0; i < 4; ++i) {
                    #pragma unroll
                    for (int p = 0; p < 4; ++p) {
                        float val = acc[i][j][p] + bvv;
                        if (ACT == 1) val = fmaxf(val, 0.0f);
                        if (ACT == 2) val = 1.0f / (1.0f + __expf(-val));
                        *(bf16*)&sbuf[(i*16 + er + p)*136 + wc*64 + j*16 + ec] = f2b(val);
                    }
                }
            }
        }
        __syncthreads();
        #pragma unroll
        for (int it = 0; it < 4; ++it) {
            const int ch = tid + it*256;
            const int row = ch >> 4, cp = (ch & 15) * 8;
            *(bf16x8*)&Cb[(size_t)(bm + half*64 + row) * ldc + bn + cp] =
                *(const bf16x8*)&sbuf[row*136 + cp];
        }
        __syncthreads();
    }
}

// ---------------- bf16 MFMA GEMM (64x64 tile, depth-4 pipeline) ----------------
// For short-K / TLP-starved GEMMs (QK^T, gate, conf, mixer). 4 LDS buffers,
// vmcnt ladder 6/4/2/0 keeps 3 tiles in flight. XOR swizzle both sides.
template<int ACT>
__global__ __launch_bounds__(256) void gemm64_bf16(
    const bf16* __restrict__ A, int lda, long long sA,
    const bf16* __restrict__ Bm, int ldb, long long sB,
    bf16* __restrict__ Cc, int ldc, long long sC,
    const float* __restrict__ bias, int K)
{
    __shared__ short sbuf[16384];        // 32 KB
    const int tid = threadIdx.x;
    const int lane = tid & 63, w = tid >> 6;
    const int wr = w >> 1, wc = w & 1;

    const int gx = gridDim.x;
    const int nwg = gx * gridDim.y;
    int id = blockIdx.y * gx + blockIdx.x;
    if ((nwg & 7) == 0) { const int cpx = nwg >> 3; id = (id & 7) * cpx + (id >> 3); }
    const int bm = (id / gx) * 64, bn = (id % gx) * 64;

    const bf16* Ab = A + (size_t)blockIdx.z * sA;
    const bf16* Bb = Bm + (size_t)blockIdx.z * sB;
    bf16* Cb = Cc + (size_t)blockIdx.z * sC;

    const int rg = lane >> 2;
    const int kswz = ((lane & 3) ^ ((rg >> 1) & 3)) * 8;

    f32x4 acc[2][2];
    const f32x4 zz = {0.f, 0.f, 0.f, 0.f};
    #pragma unroll
    for (int i = 0; i < 2; ++i)
        #pragma unroll
        for (int j = 0; j < 2; ++j) acc[i][j] = zz;

    const int fr = lane & 15;
    const int fm = lane >> 4;
    const int fslot = (fm ^ ((fr >> 1) & 3)) * 8;

    const int NI = K >> 5;

#define STAGE64(bi, kk) do {                                                           \
    gload16(Ab + (size_t)(bm + w*16 + rg) * lda + (kk) + kswz,                         \
            sbuf + (bi)*2048 + w*512);                                                 \
    gload16(Bb + (size_t)(bn + w*16 + rg) * ldb + (kk) + kswz,                         \
            sbuf + 8192 + (bi)*2048 + w*512);                                          \
    } while (0)

    STAGE64(0, 0);
    if (NI > 1) STAGE64(1, 32);
    if (NI > 2) STAGE64(2, 64);
    if (NI > 3) STAGE64(3, 96);

    for (int i = 0; i < NI; ++i) {
        const int cur = i & 3;
        if (i + 3 < NI)      asm volatile("s_waitcnt vmcnt(6)" ::: "memory");
        else if (i + 2 < NI) asm volatile("s_waitcnt vmcnt(4)" ::: "memory");
        else if (i + 1 < NI) asm volatile("s_waitcnt vmcnt(2)" ::: "memory");
        else                 asm volatile("s_waitcnt vmcnt(0)" ::: "memory");
        __builtin_amdgcn_s_barrier();
        __builtin_amdgcn_sched_barrier(0);

        bf16x8 af[2], bfr[2];
        const short* Ac = sbuf + cur * 2048;
        const short* Bc = sbuf + 8192 + cur * 2048;
        #pragma unroll
        for (int ii = 0; ii < 2; ++ii)
            af[ii] = *(const bf16x8*)&Ac[(wr*32 + ii*16 + fr)*32 + fslot];
        #pragma unroll
        for (int jj = 0; jj < 2; ++jj)
            bfr[jj] = *(const bf16x8*)&Bc[(wc*32 + jj*16 + fr)*32 + fslot];

        asm volatile("s_waitcnt lgkmcnt(0)" ::: "memory");
        __builtin_amdgcn_s_barrier();
        __builtin_amdgcn_sched_barrier(0);
        if (i + 4 < NI) STAGE64(cur, (i + 4) * 32);

        #pragma unroll
        for (int ii = 0; ii < 2; ++ii)
            #pragma unroll
            for (int jj = 0; jj < 2; ++jj)
                acc[ii][jj] = __builtin_amdgcn_mfma_f32_16x16x32_bf16(af[ii], bfr[jj], acc[ii][jj], 0, 0, 0);
    }
#undef STAGE64

    __syncthreads();
    const int er = (lane >> 4) * 4, ec = lane & 15;
    #pragma unroll
    for (int j = 0; j < 2; ++j) {
        const int col = bn + wc*32 + j*16 + ec;
        const float bvv = bias ? bias[col & 255] : 0.0f;
        #pragma unroll
        for (int i = 0; i < 2; ++i) {
            #pragma unroll
            for (int p = 0; p < 4; ++p) {
                float val = acc[i][j][p] + bvv;
                if (ACT == 1) val = fmaxf(val, 0.0f);
                if (ACT == 2) val = 1.0f / (1.0f + __expf(-val));
                *(bf16*)&sbuf[(wr*32 + i*16 + er + p)*72 + wc*32 + j*16 + ec] = f2b(val);
            }
        }
    }
    __syncthreads();
    #pragma unroll
    for (int it = 0; it < 2; ++it) {
        const int ch = tid + it*256;
        const int row = ch >> 3, cp = (ch & 7) * 8;
        *(bf16x8*)&Cb[(size_t)(bm + row) * ldc + bn + cp] =
            *(const bf16x8*)&sbuf[row*72 + cp];
    }
}

// ---------------- weight prep: transposes to bf16, one dispatch ----------------
// WT element offsets: WqkvT@0 [768,256]; WgT@196608 [256,512]; WmT@327680 [256,512];
// Wc1T@458752 [128,256]; WB2@491520 [256 n, 2304 k] = [W_rel(0..7)^T | Wroot^T].
__global__ __launch_bounds__(256) void prep_w_k(
    const float* __restrict__ Wq, const float* __restrict__ Wk, const float* __restrict__ Wv,
    const float* __restrict__ Wg, const float* __restrict__ Wm, const float* __restrict__ Wc1,
    const float* __restrict__ Wrel, const float* __restrict__ Wroot, bf16* __restrict__ WT)
{
    int t = blockIdx.x;
    const float* in; bf16* out; int Nn, ldout, kofs;
    if (t < 192)      { int wsel = t >> 6; t &= 63;
                        in = wsel == 0 ? Wq : (wsel == 1 ? Wk : Wv);
                        out = WT + wsel*65536; Nn = 256; ldout = 256; kofs = 0; }
    else if (t < 320) { t -= 192; in = Wg;  out = WT + 196608; Nn = 256; ldout = 512; kofs = 0; }
    else if (t < 448) { t -= 320; in = Wm;  out = WT + 327680; Nn = 256; ldout = 512; kofs = 0; }
    else if (t < 480) { t -= 448; in = Wc1; out = WT + 458752; Nn = 128; ldout = 256; kofs = 0; }
    else if (t < 992) { t -= 480; int r = t >> 6; t &= 63;
                        in = Wrel + (size_t)r*65536; out = WT + 491520; Nn = 256; ldout = 2304; kofs = r*256; }
    else              { t -= 992; in = Wroot; out = WT + 491520; Nn = 256; ldout = 2304; kofs = 2048; }
    const int tpr = Nn >> 5;
    const int n0 = (t % tpr) * 32, k0 = (t / tpr) * 32;
    __shared__ float tile[32][33];
    const int tx = threadIdx.x & 31, ty = threadIdx.x >> 5;
    #pragma unroll
    for (int i = 0; i < 4; ++i) {
        int r = ty + i*8;
        tile[r][tx] = in[(size_t)(k0 + r) * Nn + n0 + tx];
    }
    __syncthreads();
    #pragma unroll
    for (int i = 0; i < 4; ++i) {
        int r = ty + i*8;
        out[(size_t)(n0 + r) * ldout + kofs + k0 + tx] = f2b(tile[tx][r]);
    }
}

// ---------------- V^T: qkv V-part [1024,256] (ld 768) -> vtb [256,1024] per batch ----------------
__global__ __launch_bounds__(256) void vtrans_k(
    const bf16* __restrict__ in, bf16* __restrict__ out)
{
    __shared__ float tile[32][33];
    in  += (size_t)blockIdx.z * 786432 + 512;
    out += (size_t)blockIdx.z * 262144;
    const int n0 = blockIdx.x * 32, k0 = blockIdx.y * 32;
    const int tx = threadIdx.x & 31, ty = threadIdx.x >> 5;
    #pragma unroll
    for (int i = 0; i < 4; ++i) {
        int r = ty + i*8;
        tile[r][tx] = b2f(in[(size_t)(k0 + r) * 768 + n0 + tx]);
    }
    __syncthreads();
    #pragma unroll
    for (int i = 0; i < 4; ++i) {
        int r = ty + i*8;
        out[(size_t)(n0 + r) * 1024 + k0 + tx] = f2b(tile[tx][r]);
    }
}

// ---------------- x fp32 -> bf16 (xb, cat1 right half, cat2 left half) ----------------
__global__ __launch_bounds__(256) void cvt_x_k(const float* __restrict__ x,
    bf16* __restrict__ xb, bf16* __restrict__ cat1, bf16* __restrict__ cat2)
{
    const int i4 = (blockIdx.x * 256 + threadIdx.x) * 4;
    const float4 xv = *(const float4*)(x + i4);
    bf16 bv[4] = { f2b(xv.x), f2b(xv.y), f2b(xv.z), f2b(xv.w) };
    const ushort4 pack = *(const ushort4*)bv;
    const int row = i4 >> 8, col = i4 & 255;
    *(ushort4*)(xb + i4) = pack;
    *(ushort4*)(cat1 + (size_t)row * 512 + 256 + col) = pack;
    *(ushort4*)(cat2 + (size_t)row * 512 + col) = pack;
}

// ---------------- row softmax over 1024 bf16 scores in place (pre-scale 1/16) ----------------
__global__ __launch_bounds__(256) void softmax_k(bf16* __restrict__ s)
{
    const int row = blockIdx.x, tid = threadIdx.x;
    const int lane = tid & 63, wid = tid >> 6;
    bf16* rp = s + (size_t)row * 1024 + tid * 4;
    __shared__ float red[8];
    const ushort4 sv = *(const ushort4*)rp;
    float v0 = us2f(sv.x) * 0.0625f, v1 = us2f(sv.y) * 0.0625f;
    float v2 = us2f(sv.z) * 0.0625f, v3 = us2f(sv.w) * 0.0625f;
    float m = fmaxf(fmaxf(v0, v1), fmaxf(v2, v3));
    #pragma unroll
    for (int o = 32; o >= 1; o >>= 1) m = fmaxf(m, __shfl_xor(m, o));
    if (lane == 0) red[wid] = m;
    __syncthreads();
    const float mx = fmaxf(fmaxf(red[0], red[1]), fmaxf(red[2], red[3]));
    float e0 = __expf(v0 - mx), e1 = __expf(v1 - mx), e2 = __expf(v2 - mx), e3 = __expf(v3 - mx);
    float sm = e0 + e1 + e2 + e3;
    #pragma unroll
    for (int o = 32; o >= 1; o >>= 1) sm += __shfl_xor(sm, o);
    if (lane == 0) red[4 + wid] = sm;
    __syncthreads();
    const float inv = 1.0f / (red[4] + red[5] + red[6] + red[7]);
    bf16 ov[4] = { f2b(e0 * inv), f2b(e1 * inv), f2b(e2 * inv), f2b(e3 * inv) };
    *(ushort4*)rp = *(const ushort4*)ov;
}

// ---------------- LN over C=256 (wave per row, 4 ch/lane), bf16 in/out ----------------
template<int RELU>
__global__ __launch_bounds__(256) void ln_k(
    const bf16* __restrict__ in, bf16* __restrict__ out,
    const float* __restrict__ g, const float* __restrict__ bta)
{
    const int node = blockIdx.x * 4 + (threadIdx.x >> 6);
    const int lane = threadIdx.x & 63;
    const ushort4 iv = *(const ushort4*)(in + (size_t)node * 256 + lane * 4);
    float v0 = us2f(iv.x), v1 = us2f(iv.y), v2 = us2f(iv.z), v3 = us2f(iv.w);
    float s  = v0 + v1 + v2 + v3;
    float sq = v0*v0 + v1*v1 + v2*v2 + v3*v3;
    #pragma unroll
    for (int o = 32; o >= 1; o >>= 1) { s += __shfl_xor(s, o); sq += __shfl_xor(sq, o); }
    const float mean = s * (1.0f / 256.0f);
    const float var  = sq * (1.0f / 256.0f) - mean * mean;
    const float rs = rsqrtf(var + 1e-5f);
    const float4 gv = *(const float4*)(g + lane * 4);
    const float4 bv = *(const float4*)(bta + lane * 4);
    float y0 = (v0 - mean) * rs * gv.x + bv.x;
    float y1 = (v1 - mean) * rs * gv.y + bv.y;
    float y2 = (v2 - mean) * rs * gv.z + bv.z;
    float y3 = (v3 - mean) * rs * gv.w + bv.w;
    if (RELU) { y0 = fmaxf(y0, 0.f); y1 = fmaxf(y1, 0.f); y2 = fmaxf(y2, 0.f); y3 = fmaxf(y3, 0.f); }
    bf16 ov[4] = { f2b(y0), f2b(y1), f2b(y2), f2b(y3) };
    *(ushort4*)(out + (size_t)node * 256 + lane * 4) = *(const ushort4*)ov;
}

// ---------------- gated blend + LN (wave per row; residual from bf16 xb) ----------------
__global__ __launch_bounds__(256) void blend_ln_k(
    const bf16* __restrict__ gate, const bf16* __restrict__ cat1,
    const bf16* __restrict__ xb, bf16* __restrict__ valid,
    const float* __restrict__ g, const float* __restrict__ bta)
{
    const int node = blockIdx.x * 4 + (threadIdx.x >> 6);
    const int lane = threadIdx.x & 63;
    const ushort4 gt4 = *(const ushort4*)(gate + (size_t)node * 256 + lane * 4);
    const ushort4 ao4 = *(const ushort4*)(cat1 + (size_t)node * 512 + lane * 4);
    const ushort4 xv4 = *(const ushort4*)(xb + (size_t)node * 256 + lane * 4);
    float g0 = us2f(gt4.x), g1 = us2f(gt4.y), g2 = us2f(gt4.z), g3 = us2f(gt4.w);
    float v0 = g0 * us2f(ao4.x) + (1.f - g0) * us2f(xv4.x);
    float v1 = g1 * us2f(ao4.y) + (1.f - g1) * us2f(xv4.y);
    float v2 = g2 * us2f(ao4.z) + (1.f - g2) * us2f(xv4.z);
    float v3 = g3 * us2f(ao4.w) + (1.f - g3) * us2f(xv4.w);
    float s  = v0 + v1 + v2 + v3;
    float sq = v0*v0 + v1*v1 + v2*v2 + v3*v3;
    #pragma unroll
    for (int o = 32; o >= 1; o >>= 1) { s += __shfl_xor(s, o); sq += __shfl_xor(sq, o); }
    const float mean = s * (1.0f / 256.0f);
    const float var  = sq * (1.0f / 256.0f) - mean * mean;
    const float rs = rsqrtf(var + 1e-5f);
    const float4 gv = *(const float4*)(g + lane * 4);
    const float4 bv = *(const float4*)(bta + lane * 4);
    bf16 ov[4] = { f2b((v0 - mean) * rs * gv.x + bv.x), f2b((v1 - mean) * rs * gv.y + bv.y),
                   f2b((v2 - mean) * rs * gv.z + bv.z), f2b((v3 - mean) * rs * gv.w + bv.w) };
    *(ushort4*)(valid + (size_t)node * 256 + lane * 4) = *(const ushort4*)ov;
}

// ---------------- confidence layer2 + weighted (wave per node) ----------------
__global__ __launch_bounds__(256) void conf_w_k(
    const bf16* __restrict__ t1, const float* __restrict__ Wc2, const float* __restrict__ bc2,
    const bf16* __restrict__ valid, float* __restrict__ conf, bf16* __restrict__ cat2)
{
    const int node = blockIdx.x * 4 + (threadIdx.x >> 6);
    const int lane = threadIdx.x & 63;
    float a = b2f(t1[(size_t)node * 128 + lane]) * Wc2[lane]
            + b2f(t1[(size_t)node * 128 + 64 + lane]) * Wc2[64 + lane];
    #pragma unroll
    for (int o = 32; o >= 1; o >>= 1) a += __shfl_xor(a, o);
    const float c = 1.0f / (1.0f + __expf(-(a + bc2[0])));
    if (lane == 0) conf[node] = c;
    const ushort4 vv = *(const ushort4*)(valid + (size_t)node * 256 + lane * 4);
    bf16 ov[4] = { f2b(us2f(vv.x) * c), f2b(us2f(vv.y) * c), f2b(us2f(vv.z) * c), f2b(us2f(vv.w) * c) };
    *(ushort4*)(cat2 + (size_t)node * 512 + 256 + lane * 4) = *(const ushort4*)ov;
}

// ---------------- CSR8 build: per-(dst,rel) counts, scan, fill ----------------
__global__ __launch_bounds__(256) void count8_k(
    const int* __restrict__ dst, const int* __restrict__ et, int* __restrict__ cnt8)
{
    const int e = blockIdx.x * 256 + threadIdx.x;
    if (e < E_) atomicAdd(&cnt8[dst[e] * 8 + et[e]], 1);
}

// single block: exclusive prefix over 131072 (dst,rel) counts
__global__ __launch_bounds__(256) void scan8_k(
    const int* __restrict__ cnt8, int* __restrict__ rowptr8, int* __restrict__ cursor8)
{
    __shared__ int part[256];
    const int tid = threadIdx.x;
    const int base = tid * 512;
    int s = 0;
    for (int i = 0; i < 512; ++i) s += cnt8[base + i];
    part[tid] = s; __syncthreads();
    for (int off = 1; off < 256; off <<= 1) {
        int t = (tid >= off) ? part[tid - off] : 0;
        __syncthreads();
        part[tid] += t;
        __syncthreads();
    }
    int run = (tid == 0) ? 0 : part[tid - 1];
    for (int i = 0; i < 512; ++i) {
        rowptr8[base + i] = run;
        cursor8[base + i] = run;
        run += cnt8[base + i];
    }
    if (tid == 255) rowptr8[BN_ * 8] = run;
}

__global__ __launch_bounds__(256) void fill8_k(
    const int* __restrict__ src, const int* __restrict__ dst, const int* __restrict__ et,
    int* __restrict__ cursor8, int* __restrict__ elist)
{
    const int e = blockIdx.x * 256 + threadIdx.x;
    if (e < E_) {
        const int pos = atomicAdd(&cursor8[dst[e] * 8 + et[e]], 1);
        elist[pos] = src[e];
    }
}

// ---------------- RGCN aggregate-first: S[node] = [mean_r xn rows (8x256) | xn row] ----------------
// Wave per node. Static 8-relation unroll (rule #20); 2-deep edge unroll.
// Reads xn (8 MB, L2/LLC-hot) instead of a 75 MB transformed buffer.
__global__ __launch_bounds__(256) void gather_sum_k(
    const int* __restrict__ rowptr8, const int* __restrict__ elist,
    const bf16* __restrict__ xn, bf16* __restrict__ S)
{
    const int node = blockIdx.x * 4 + (threadIdx.x >> 6);
    const int lane = threadIdx.x & 63;
    bf16* Srow = S + (size_t)node * 2304;
    // tail: raw xn row (feeds the Wroot k-columns)
    *(ushort4*)(Srow + 2048 + lane * 4) = *(const ushort4*)(xn + (size_t)node * 256 + lane * 4);
    const int base = node * 8;
    #pragma unroll
    for (int r = 0; r < 8; ++r) {
        const int e0 = rowptr8[base + r], e1 = rowptr8[base + r + 1];
        float a0 = 0.f, a1 = 0.f, a2 = 0.f, a3 = 0.f;
        int e = e0;
        for (; e + 1 < e1; e += 2) {
            const int s0 = elist[e], s1 = elist[e + 1];
            const ushort4 h0 = *(const ushort4*)(xn + (size_t)s0 * 256 + lane * 4);
            const ushort4 h1 = *(const ushort4*)(xn + (size_t)s1 * 256 + lane * 4);
            a0 += us2f(h0.x) + us2f(h1.x);
            a1 += us2f(h0.y) + us2f(h1.y);
            a2 += us2f(h0.z) + us2f(h1.z);
            a3 += us2f(h0.w) + us2f(h1.w);
        }
        if (e < e1) {
            const ushort4 hv = *(const ushort4*)(xn + (size_t)elist[e] * 256 + lane * 4);
            a0 += us2f(hv.x); a1 += us2f(hv.y); a2 += us2f(hv.z); a3 += us2f(hv.w);
        }
        const float inv = 1.0f / fmaxf((float)(e1 - e0), 1.0f);
        bf16 ov[4] = { f2b(a0 * inv), f2b(a1 * inv), f2b(a2 * inv), f2b(a3 * inv) };
        *(ushort4*)(Srow + r * 256 + lane * 4) = *(const ushort4*)ov;
    }
}

// ---------------- pooling stage 1 ----------------
__global__ __launch_bounds__(256) void pool1_k(
    const bf16* __restrict__ xr, const float* __restrict__ conf, float* __restrict__ partial)
{
    const int b = blockIdx.x, chunk = blockIdx.y, c = threadIdx.x;
    float acc = 0.0f;
    for (int n = 0; n < 64; ++n) {
        const int node = b * 1024 + chunk * 64 + n;
        acc += conf[node] * b2f(xr[(size_t)node * 256 + c]);
    }
    partial[(size_t)(b * 16 + chunk) * 256 + c] = acc;
}

// ---------------- pooling stage 2 + head ----------------
__global__ __launch_bounds__(256) void pool2_k(
    const float* __restrict__ partial, const float* __restrict__ conf,
    const float* __restrict__ Wh, const float* __restrict__ bh, float* __restrict__ out)
{
    const int b = blockIdx.x, tid = threadIdx.x;
    __shared__ float red[256];
    __shared__ float pooled[256];
    float pc = 0.0f;
    for (int ch = 0; ch < 16; ++ch) pc += partial[(size_t)(b * 16 + ch) * 256 + tid];
    float s = conf[b * 1024 + tid] + conf[b * 1024 + 256 + tid]
            + conf[b * 1024 + 512 + tid] + conf[b * 1024 + 768 + tid];
    red[tid] = s; __syncthreads();
    for (int st = 128; st > 0; st >>= 1) { if (tid < st) red[tid] += red[tid + st]; __syncthreads(); }
    const float denom = fmaxf(red[0], 1e-8f);
    pooled[tid] = pc / denom;
    __syncthreads();
    if (tid < NS_) {
        float o = bh[tid];
        for (int c = 0; c < 256; ++c) o += pooled[c] * Wh[c * NS_ + tid];
        out[b * NS_ + tid] = o;
    }
}

extern "C" void kernel_launch(void* const* d_in, const int* in_sizes, int n_in,
                              void* d_out, int out_size, void* d_ws, size_t ws_size,
                              hipStream_t stream) {
    const float* x    = (const float*)d_in[0];
    const int*   ei   = (const int*)d_in[1];
    const int*   et   = (const int*)d_in[2];
    const float* Wq   = (const float*)d_in[3];  const float* bq  = (const float*)d_in[4];
    const float* Wk   = (const float*)d_in[5];  const float* bk  = (const float*)d_in[6];
    const float* Wv   = (const float*)d_in[7];  const float* bv  = (const float*)d_in[8];
    const float* Wg   = (const float*)d_in[9];  const float* bg  = (const float*)d_in[10];
    const float* lag  = (const float*)d_in[11]; const float* lab = (const float*)d_in[12];
    const float* Wc1  = (const float*)d_in[13]; const float* bc1 = (const float*)d_in[14];
    const float* Wc2  = (const float*)d_in[15]; const float* bc2 = (const float*)d_in[16];
    const float* Wm   = (const float*)d_in[17]; const float* bm  = (const float*)d_in[18];
    const float* l1g  = (const float*)d_in[19]; const float* l1b = (const float*)d_in[20];
    const float* Wrel = (const float*)d_in[21]; const float* Wroot = (const float*)d_in[22];
    const float* brg  = (const float*)d_in[23];
    const float* l2g  = (const float*)d_in[24]; const float* l2b = (const float*)d_in[25];
    const float* Wh   = (const float*)d_in[26]; const float* bh  = (const float*)d_in[27];
    const int* esrc = ei;
    const int* edst = ei + E_;

    char* w8 = (char*)d_ws;
    bf16*  qkv   = (bf16*)(w8 + 0);            // [16384,768]
    bf16*  Sbig  = (bf16*)(w8 + 0);            // [16384,2304] 75.5 MB (qkv/sP/cat1 dead by then)
    bf16*  sP    = (bf16*)(w8 + 25165824);     // [16x1024x1024]
    bf16*  cat1  = (bf16*)(w8 + 58720256);     // [aout|xb] ld 512
    bf16*  cat2  = (bf16*)(w8 + 75497472);     // [xb|weighted] ld 512
    bf16*  gate  = (bf16*)(w8 + 92274688);     // 8 MB; reused as aggb after blend
    bf16*  valid = (bf16*)(w8 + 100663296);
    bf16*  t1    = (bf16*)(w8 + 109051904);
    bf16*  xm    = (bf16*)(w8 + 113246208);
    bf16*  xb    = (bf16*)(w8 + 121634816);
    bf16*  xn    = (bf16*)(w8 + 130023424);
    bf16*  vtb   = (bf16*)(w8 + 138412032);
    bf16*  xr    = (bf16*)(w8 + 146800640);
    float* conf  = (float*)(w8 + 155189248);
    float* part  = (float*)(w8 + 155254784);
    bf16*  WT    = (bf16*)(w8 + 155516928);    // 2,162,688 B -> ends 157,679,616
    int*  cnt8i   = (int*)(w8 + 157679616);    // 524,288 B   -> ends 158,203,904
    int*  rowptr8 = (int*)(w8 + 158203904);    // 524,292 B (+pad) -> cursor8 @ +524,544
    int*  cursor8 = (int*)(w8 + 158728448);    // 524,288 B   -> ends 159,252,736
    int*  elist   = (int*)(w8 + 159252736);    // 1,048,576 B -> ends 160,301,312
    bf16* WqkvT = WT;                  // [768,256]
    bf16* WgT   = WT + 196608;         // [256,512]
    bf16* WmT   = WT + 327680;         // [256,512]
    bf16* Wc1T  = WT + 458752;         // [128,256]
    bf16* WB2   = WT + 491520;         // [256,2304]
    bf16* aggb  = gate;                // agg bf16 (gate dead after blend)
    float* outp = (float*)d_out;

    dim3 blk(256);

    // --- prep: weights, x conversion, CSR8 build ---
    prep_w_k<<<1056, blk, 0, stream>>>(Wq, Wk, Wv, Wg, Wm, Wc1, Wrel, Wroot, WT);
    cvt_x_k<<<BNC_ / 1024, blk, 0, stream>>>(x, xb, cat1, cat2);
    hipMemsetAsync(cnt8i, 0, (size_t)BN_ * 8 * sizeof(int), stream);
    count8_k<<<E_ / 256, blk, 0, stream>>>(edst, et, cnt8i);
    scan8_k<<<1, blk, 0, stream>>>(cnt8i, rowptr8, cursor8);
    fill8_k<<<E_ / 256, blk, 0, stream>>>(esrc, edst, et, cursor8, elist);

    // --- fused QKV projection: qkv[16384,768] ---
    gemm_bf16<0><<<dim3(6, 128, 1), blk, 0, stream>>>(
        xb, 256, 0, WqkvT, 256, 0, qkv, 768, 0, bq, bk, bv, 256);
    vtrans_k<<<dim3(8, 32, 16), blk, 0, stream>>>(qkv, vtb);

    // --- attention: QK^T (64-tile depth-4, 4096 blocks), softmax, PV (128-tile) ---
    gemm64_bf16<0><<<dim3(16, 16, 16), blk, 0, stream>>>(
        qkv, 768, 786432, qkv + 256, 768, 786432, sP, 1024, 1048576, nullptr, 256);
    softmax_k<<<BN_, blk, 0, stream>>>(sP);
    gemm_bf16<0><<<dim3(2, 8, 16), blk, 0, stream>>>(
        sP, 1024, 1048576, vtb, 1024, 262144, cat1, 512, 524288, nullptr, nullptr, nullptr, 1024);

    // --- gate (64-tile depth-4), blend+LN ---
    gemm64_bf16<2><<<dim3(4, 256, 1), blk, 0, stream>>>(
        cat1, 512, 0, WgT, 512, 0, gate, 256, 0, bg, 512);
    blend_ln_k<<<BN_ / 4, blk, 0, stream>>>(gate, cat1, xb, valid, lag, lab);

    // --- confidence (64-tile depth-4) + weighted ---
    gemm64_bf16<1><<<dim3(2, 256, 1), blk, 0, stream>>>(
        valid, 256, 0, Wc1T, 256, 0, t1, 128, 0, bc1, 256);
    conf_w_k<<<BN_ / 4, blk, 0, stream>>>(t1, Wc2, bc2, valid, conf, cat2);

    // --- mixer (64-tile depth-4) + LN1 ---
    gemm64_bf16<1><<<dim3(4, 256, 1), blk, 0, stream>>>(
        cat2, 512, 0, WmT, 512, 0, xm, 256, 0, bm, 512);
    ln_k<0><<<BN_ / 4, blk, 0, stream>>>(xm, xn, l1g, l1b);

    // --- RGCN aggregate-first: gather-mean from hot xn, then ONE long-K GEMM ---
    gather_sum_k<<<BN_ / 4, blk, 0, stream>>>(rowptr8, elist, xn, Sbig);
    gemm_bf16<0><<<dim3(2, 128, 1), blk, 0, stream>>>(
        Sbig, 2304, 0, WB2, 2304, 0, aggb, 256, 0, brg, nullptr, nullptr, 2304);
    ln_k<1><<<BN_ / 4, blk, 0, stream>>>(aggb, xr, l2g, l2b);

    // --- pool + head ---
    pool1_k<<<dim3(B_, 16), blk, 0, stream>>>(xr, conf, part);
    pool2_k<<<B_, blk, 0, stream>>>(part, conf, Wh, bh, outp);
}

// Round 15
// 259.100 us; speedup vs baseline: 1.2478x; 1.2478x over previous
//
#include <hip/hip_runtime.h>
#include <hip/hip_bf16.h>

#define B_ 16
#define N_ 1024
#define C_ 256
#define R_ 8
#define E_ 262144
#define NS_ 32
#define BN_ (B_*N_)
#define BNC_ (BN_*C_)

typedef __hip_bfloat16 bf16;
typedef __attribute__((ext_vector_type(4))) float f32x4;
typedef __attribute__((ext_vector_type(8))) short bf16x8;

__device__ __forceinline__ float b2f(bf16 x) { return __bfloat162float(x); }
__device__ __forceinline__ bf16  f2b(float x) { return __float2bfloat16(x); }
__device__ __forceinline__ float us2f(unsigned short u) { return __uint_as_float((unsigned)u << 16); }

// async global->LDS, 16B per lane (wave-uniform LDS base + lane*16 implicit)
__device__ __forceinline__ void gload16(const void* g, void* l) {
    auto gp = (const __attribute__((address_space(1))) void*)(unsigned long long)g;
    auto lp = (__attribute__((address_space(3))) void*)(unsigned)(unsigned long long)l;
    __builtin_amdgcn_global_load_lds(gp, lp, 16, 0, 0);
}

// ---------------- bf16 MFMA GEMM (128x128 tile): C = act(A @ B^T + bias) ----------------
// Depth-3 pipeline (48 KB LDS), vmcnt ladder 8/4/0; XOR slot swizzle both sides;
// XCD-aware block swizzle (bijective when nwg % 8 == 0).
template<int ACT>
__global__ __launch_bounds__(256) void gemm_bf16(
    const bf16* __restrict__ A, int lda, long long sA,
    const bf16* __restrict__ Bm, int ldb, long long sB,
    bf16* __restrict__ Cc, int ldc, long long sC,
    const float* __restrict__ bias, const float* __restrict__ bias2,
    const float* __restrict__ bias3, int K)
{
    __shared__ short sbuf[24576];        // 48 KB
    const int tid = threadIdx.x;
    const int lane = tid & 63, w = tid >> 6;
    const int wr = w >> 1, wc = w & 1;

    const int gx = gridDim.x;
    const int nwg = gx * gridDim.y;
    int id = blockIdx.y * gx + blockIdx.x;
    if ((nwg & 7) == 0) { const int cpx = nwg >> 3; id = (id & 7) * cpx + (id >> 3); }
    const int bm = (id / gx) * 128, bn = (id % gx) * 128;

    const bf16* Ab = A + (size_t)blockIdx.z * sA;
    const bf16* Bb = Bm + (size_t)blockIdx.z * sB;
    bf16* Cb = Cc + (size_t)blockIdx.z * sC;

    const int rg = lane >> 2;
    const int kswz = ((lane & 3) ^ ((rg >> 1) & 3)) * 8;

    f32x4 acc[4][4];
    const f32x4 zz = {0.f, 0.f, 0.f, 0.f};
    #pragma unroll
    for (int i = 0; i < 4; ++i)
        #pragma unroll
        for (int j = 0; j < 4; ++j) acc[i][j] = zz;

    const int fr = lane & 15;
    const int fm = lane >> 4;
    const int fslot = (fm ^ ((fr >> 1) & 3)) * 8;

    const int NI = K >> 5;

#define STAGE_AB(bi, kk) do {                                                          \
    _Pragma("unroll")                                                                  \
    for (int t_ = 0; t_ < 2; ++t_) {                                                   \
        gload16(Ab + (size_t)(bm + t_*64 + w*16 + rg) * lda + (kk) + kswz,             \
                sbuf + (bi)*4096 + t_*2048 + w*512);                                   \
        gload16(Bb + (size_t)(bn + t_*64 + w*16 + rg) * ldb + (kk) + kswz,             \
                sbuf + 12288 + (bi)*4096 + t_*2048 + w*512);                           \
    } } while (0)

    STAGE_AB(0, 0);
    if (NI > 1) STAGE_AB(1, 32);
    if (NI > 2) STAGE_AB(2, 64);

    int cur = 0;
    for (int i = 0; i < NI; ++i) {
        if (i + 2 < NI)      asm volatile("s_waitcnt vmcnt(8)" ::: "memory");
        else if (i + 1 < NI) asm volatile("s_waitcnt vmcnt(4)" ::: "memory");
        else                 asm volatile("s_waitcnt vmcnt(0)" ::: "memory");
        __builtin_amdgcn_s_barrier();
        __builtin_amdgcn_sched_barrier(0);

        bf16x8 af[4], bfr[4];
        const short* Ac = sbuf + cur * 4096;
        const short* Bc = sbuf + 12288 + cur * 4096;
        #pragma unroll
        for (int ii = 0; ii < 4; ++ii)
            af[ii] = *(const bf16x8*)&Ac[(wr*64 + ii*16 + fr)*32 + fslot];
        #pragma unroll
        for (int jj = 0; jj < 4; ++jj)
            bfr[jj] = *(const bf16x8*)&Bc[(wc*64 + jj*16 + fr)*32 + fslot];

        asm volatile("s_waitcnt lgkmcnt(0)" ::: "memory");
        __builtin_amdgcn_s_barrier();
        __builtin_amdgcn_sched_barrier(0);
        if (i + 3 < NI) STAGE_AB(cur, (i + 3) * 32);

        #pragma unroll
        for (int ii = 0; ii < 4; ++ii)
            #pragma unroll
            for (int jj = 0; jj < 4; ++jj)
                acc[ii][jj] = __builtin_amdgcn_mfma_f32_16x16x32_bf16(af[ii], bfr[jj], acc[ii][jj], 0, 0, 0);
        cur = (cur == 2) ? 0 : cur + 1;
    }
#undef STAGE_AB

    __syncthreads();
    const int er = (lane >> 4) * 4, ec = lane & 15;
    #pragma unroll
    for (int half = 0; half < 2; ++half) {
        if (wr == half) {
            #pragma unroll
            for (int j = 0; j < 4; ++j) {
                const int col = bn + wc*64 + j*16 + ec;
                float bvv = 0.0f;
                if (bias) {
                    const int seg = col >> 8;
                    const float* bp = (seg == 0) ? bias : (seg == 1 ? bias2 : bias3);
                    bvv = bp[col & 255];
                }
                #pragma unroll
                for (int i = 0; i < 4; ++i) {
                    #pragma unroll
                    for (int p = 0; p < 4; ++p) {
                        float val = acc[i][j][p] + bvv;
                        if (ACT == 1) val = fmaxf(val, 0.0f);
                        if (ACT == 2) val = 1.0f / (1.0f + __expf(-val));
                        *(bf16*)&sbuf[(i*16 + er + p)*136 + wc*64 + j*16 + ec] = f2b(val);
                    }
                }
            }
        }
        __syncthreads();
        #pragma unroll
        for (int it = 0; it < 4; ++it) {
            const int ch = tid + it*256;
            const int row = ch >> 4, cp = (ch & 15) * 8;
            *(bf16x8*)&Cb[(size_t)(bm + half*64 + row) * ldc + bn + cp] =
                *(const bf16x8*)&sbuf[row*136 + cp];
        }
        __syncthreads();
    }
}

// ---------------- bf16 MFMA GEMM (64x64 tile, depth-4 pipeline) ----------------
template<int ACT>
__global__ __launch_bounds__(256) void gemm64_bf16(
    const bf16* __restrict__ A, int lda, long long sA,
    const bf16* __restrict__ Bm, int ldb, long long sB,
    bf16* __restrict__ Cc, int ldc, long long sC,
    const float* __restrict__ bias, int K)
{
    __shared__ short sbuf[16384];        // 32 KB
    const int tid = threadIdx.x;
    const int lane = tid & 63, w = tid >> 6;
    const int wr = w >> 1, wc = w & 1;

    const int gx = gridDim.x;
    const int nwg = gx * gridDim.y;
    int id = blockIdx.y * gx + blockIdx.x;
    if ((nwg & 7) == 0) { const int cpx = nwg >> 3; id = (id & 7) * cpx + (id >> 3); }
    const int bm = (id / gx) * 64, bn = (id % gx) * 64;

    const bf16* Ab = A + (size_t)blockIdx.z * sA;
    const bf16* Bb = Bm + (size_t)blockIdx.z * sB;
    bf16* Cb = Cc + (size_t)blockIdx.z * sC;

    const int rg = lane >> 2;
    const int kswz = ((lane & 3) ^ ((rg >> 1) & 3)) * 8;

    f32x4 acc[2][2];
    const f32x4 zz = {0.f, 0.f, 0.f, 0.f};
    #pragma unroll
    for (int i = 0; i < 2; ++i)
        #pragma unroll
        for (int j = 0; j < 2; ++j) acc[i][j] = zz;

    const int fr = lane & 15;
    const int fm = lane >> 4;
    const int fslot = (fm ^ ((fr >> 1) & 3)) * 8;

    const int NI = K >> 5;

#define STAGE64(bi, kk) do {                                                           \
    gload16(Ab + (size_t)(bm + w*16 + rg) * lda + (kk) + kswz,                         \
            sbuf + (bi)*2048 + w*512);                                                 \
    gload16(Bb + (size_t)(bn + w*16 + rg) * ldb + (kk) + kswz,                         \
            sbuf + 8192 + (bi)*2048 + w*512);                                          \
    } while (0)

    STAGE64(0, 0);
    if (NI > 1) STAGE64(1, 32);
    if (NI > 2) STAGE64(2, 64);
    if (NI > 3) STAGE64(3, 96);

    for (int i = 0; i < NI; ++i) {
        const int cur = i & 3;
        if (i + 3 < NI)      asm volatile("s_waitcnt vmcnt(6)" ::: "memory");
        else if (i + 2 < NI) asm volatile("s_waitcnt vmcnt(4)" ::: "memory");
        else if (i + 1 < NI) asm volatile("s_waitcnt vmcnt(2)" ::: "memory");
        else                 asm volatile("s_waitcnt vmcnt(0)" ::: "memory");
        __builtin_amdgcn_s_barrier();
        __builtin_amdgcn_sched_barrier(0);

        bf16x8 af[2], bfr[2];
        const short* Ac = sbuf + cur * 2048;
        const short* Bc = sbuf + 8192 + cur * 2048;
        #pragma unroll
        for (int ii = 0; ii < 2; ++ii)
            af[ii] = *(const bf16x8*)&Ac[(wr*32 + ii*16 + fr)*32 + fslot];
        #pragma unroll
        for (int jj = 0; jj < 2; ++jj)
            bfr[jj] = *(const bf16x8*)&Bc[(wc*32 + jj*16 + fr)*32 + fslot];

        asm volatile("s_waitcnt lgkmcnt(0)" ::: "memory");
        __builtin_amdgcn_s_barrier();
        __builtin_amdgcn_sched_barrier(0);
        if (i + 4 < NI) STAGE64(cur, (i + 4) * 32);

        #pragma unroll
        for (int ii = 0; ii < 2; ++ii)
            #pragma unroll
            for (int jj = 0; jj < 2; ++jj)
                acc[ii][jj] = __builtin_amdgcn_mfma_f32_16x16x32_bf16(af[ii], bfr[jj], acc[ii][jj], 0, 0, 0);
    }
#undef STAGE64

    __syncthreads();
    const int er = (lane >> 4) * 4, ec = lane & 15;
    #pragma unroll
    for (int j = 0; j < 2; ++j) {
        const int col = bn + wc*32 + j*16 + ec;
        const float bvv = bias ? bias[col & 255] : 0.0f;
        #pragma unroll
        for (int i = 0; i < 2; ++i) {
            #pragma unroll
            for (int p = 0; p < 4; ++p) {
                float val = acc[i][j][p] + bvv;
                if (ACT == 1) val = fmaxf(val, 0.0f);
                if (ACT == 2) val = 1.0f / (1.0f + __expf(-val));
                *(bf16*)&sbuf[(wr*32 + i*16 + er + p)*72 + wc*32 + j*16 + ec] = f2b(val);
            }
        }
    }
    __syncthreads();
    #pragma unroll
    for (int it = 0; it < 2; ++it) {
        const int ch = tid + it*256;
        const int row = ch >> 3, cp = (ch & 7) * 8;
        *(bf16x8*)&Cb[(size_t)(bm + row) * ldc + bn + cp] =
            *(const bf16x8*)&sbuf[row*72 + cp];
    }
}

// ---------------- weight prep: transposes to bf16, one dispatch ----------------
__global__ __launch_bounds__(256) void prep_w_k(
    const float* __restrict__ Wq, const float* __restrict__ Wk, const float* __restrict__ Wv,
    const float* __restrict__ Wg, const float* __restrict__ Wm, const float* __restrict__ Wc1,
    const float* __restrict__ Wrel, const float* __restrict__ Wroot, bf16* __restrict__ WT)
{
    int t = blockIdx.x;
    const float* in; bf16* out; int Nn, ldout, kofs;
    if (t < 192)      { int wsel = t >> 6; t &= 63;
                        in = wsel == 0 ? Wq : (wsel == 1 ? Wk : Wv);
                        out = WT + wsel*65536; Nn = 256; ldout = 256; kofs = 0; }
    else if (t < 320) { t -= 192; in = Wg;  out = WT + 196608; Nn = 256; ldout = 512; kofs = 0; }
    else if (t < 448) { t -= 320; in = Wm;  out = WT + 327680; Nn = 256; ldout = 512; kofs = 0; }
    else if (t < 480) { t -= 448; in = Wc1; out = WT + 458752; Nn = 128; ldout = 256; kofs = 0; }
    else if (t < 992) { t -= 480; int r = t >> 6; t &= 63;
                        in = Wrel + (size_t)r*65536; out = WT + 491520; Nn = 256; ldout = 2304; kofs = r*256; }
    else              { t -= 992; in = Wroot; out = WT + 491520; Nn = 256; ldout = 2304; kofs = 2048; }
    const int tpr = Nn >> 5;
    const int n0 = (t % tpr) * 32, k0 = (t / tpr) * 32;
    __shared__ float tile[32][33];
    const int tx = threadIdx.x & 31, ty = threadIdx.x >> 5;
    #pragma unroll
    for (int i = 0; i < 4; ++i) {
        int r = ty + i*8;
        tile[r][tx] = in[(size_t)(k0 + r) * Nn + n0 + tx];
    }
    __syncthreads();
    #pragma unroll
    for (int i = 0; i < 4; ++i) {
        int r = ty + i*8;
        out[(size_t)(n0 + r) * ldout + kofs + k0 + tx] = f2b(tile[tx][r]);
    }
}

// ---------------- V^T: qkv V-part [1024,256] (ld 768) -> vtb [256,1024] per batch ----------------
__global__ __launch_bounds__(256) void vtrans_k(
    const bf16* __restrict__ in, bf16* __restrict__ out)
{
    __shared__ float tile[32][33];
    in  += (size_t)blockIdx.z * 786432 + 512;
    out += (size_t)blockIdx.z * 262144;
    const int n0 = blockIdx.x * 32, k0 = blockIdx.y * 32;
    const int tx = threadIdx.x & 31, ty = threadIdx.x >> 5;
    #pragma unroll
    for (int i = 0; i < 4; ++i) {
        int r = ty + i*8;
        tile[r][tx] = b2f(in[(size_t)(k0 + r) * 768 + n0 + tx]);
    }
    __syncthreads();
    #pragma unroll
    for (int i = 0; i < 4; ++i) {
        int r = ty + i*8;
        out[(size_t)(n0 + r) * 1024 + k0 + tx] = f2b(tile[tx][r]);
    }
}

// ---------------- x fp32 -> bf16 (xb, cat1 right half, cat2 left half) ----------------
__global__ __launch_bounds__(256) void cvt_x_k(const float* __restrict__ x,
    bf16* __restrict__ xb, bf16* __restrict__ cat1, bf16* __restrict__ cat2)
{
    const int i4 = (blockIdx.x * 256 + threadIdx.x) * 4;
    const float4 xv = *(const float4*)(x + i4);
    bf16 bv[4] = { f2b(xv.x), f2b(xv.y), f2b(xv.z), f2b(xv.w) };
    const ushort4 pack = *(const ushort4*)bv;
    const int row = i4 >> 8, col = i4 & 255;
    *(ushort4*)(xb + i4) = pack;
    *(ushort4*)(cat1 + (size_t)row * 512 + 256 + col) = pack;
    *(ushort4*)(cat2 + (size_t)row * 512 + col) = pack;
}

// ---------------- row softmax over 1024 bf16 scores in place (pre-scale 1/16) ----------------
__global__ __launch_bounds__(256) void softmax_k(bf16* __restrict__ s)
{
    const int row = blockIdx.x, tid = threadIdx.x;
    const int lane = tid & 63, wid = tid >> 6;
    bf16* rp = s + (size_t)row * 1024 + tid * 4;
    __shared__ float red[8];
    const ushort4 sv = *(const ushort4*)rp;
    float v0 = us2f(sv.x) * 0.0625f, v1 = us2f(sv.y) * 0.0625f;
    float v2 = us2f(sv.z) * 0.0625f, v3 = us2f(sv.w) * 0.0625f;
    float m = fmaxf(fmaxf(v0, v1), fmaxf(v2, v3));
    #pragma unroll
    for (int o = 32; o >= 1; o >>= 1) m = fmaxf(m, __shfl_xor(m, o));
    if (lane == 0) red[wid] = m;
    __syncthreads();
    const float mx = fmaxf(fmaxf(red[0], red[1]), fmaxf(red[2], red[3]));
    float e0 = __expf(v0 - mx), e1 = __expf(v1 - mx), e2 = __expf(v2 - mx), e3 = __expf(v3 - mx);
    float sm = e0 + e1 + e2 + e3;
    #pragma unroll
    for (int o = 32; o >= 1; o >>= 1) sm += __shfl_xor(sm, o);
    if (lane == 0) red[4 + wid] = sm;
    __syncthreads();
    const float inv = 1.0f / (red[4] + red[5] + red[6] + red[7]);
    bf16 ov[4] = { f2b(e0 * inv), f2b(e1 * inv), f2b(e2 * inv), f2b(e3 * inv) };
    *(ushort4*)rp = *(const ushort4*)ov;
}

// ---------------- LN over C=256 (wave per row, 4 ch/lane), bf16 in/out ----------------
template<int RELU>
__global__ __launch_bounds__(256) void ln_k(
    const bf16* __restrict__ in, bf16* __restrict__ out,
    const float* __restrict__ g, const float* __restrict__ bta)
{
    const int node = blockIdx.x * 4 + (threadIdx.x >> 6);
    const int lane = threadIdx.x & 63;
    const ushort4 iv = *(const ushort4*)(in + (size_t)node * 256 + lane * 4);
    float v0 = us2f(iv.x), v1 = us2f(iv.y), v2 = us2f(iv.z), v3 = us2f(iv.w);
    float s  = v0 + v1 + v2 + v3;
    float sq = v0*v0 + v1*v1 + v2*v2 + v3*v3;
    #pragma unroll
    for (int o = 32; o >= 1; o >>= 1) { s += __shfl_xor(s, o); sq += __shfl_xor(sq, o); }
    const float mean = s * (1.0f / 256.0f);
    const float var  = sq * (1.0f / 256.0f) - mean * mean;
    const float rs = rsqrtf(var + 1e-5f);
    const float4 gv = *(const float4*)(g + lane * 4);
    const float4 bv = *(const float4*)(bta + lane * 4);
    float y0 = (v0 - mean) * rs * gv.x + bv.x;
    float y1 = (v1 - mean) * rs * gv.y + bv.y;
    float y2 = (v2 - mean) * rs * gv.z + bv.z;
    float y3 = (v3 - mean) * rs * gv.w + bv.w;
    if (RELU) { y0 = fmaxf(y0, 0.f); y1 = fmaxf(y1, 0.f); y2 = fmaxf(y2, 0.f); y3 = fmaxf(y3, 0.f); }
    bf16 ov[4] = { f2b(y0), f2b(y1), f2b(y2), f2b(y3) };
    *(ushort4*)(out + (size_t)node * 256 + lane * 4) = *(const ushort4*)ov;
}

// ---------------- gated blend + LN (wave per row; residual from bf16 xb) ----------------
__global__ __launch_bounds__(256) void blend_ln_k(
    const bf16* __restrict__ gate, const bf16* __restrict__ cat1,
    const bf16* __restrict__ xb, bf16* __restrict__ valid,
    const float* __restrict__ g, const float* __restrict__ bta)
{
    const int node = blockIdx.x * 4 + (threadIdx.x >> 6);
    const int lane = threadIdx.x & 63;
    const ushort4 gt4 = *(const ushort4*)(gate + (size_t)node * 256 + lane * 4);
    const ushort4 ao4 = *(const ushort4*)(cat1 + (size_t)node * 512 + lane * 4);
    const ushort4 xv4 = *(const ushort4*)(xb + (size_t)node * 256 + lane * 4);
    float g0 = us2f(gt4.x), g1 = us2f(gt4.y), g2 = us2f(gt4.z), g3 = us2f(gt4.w);
    float v0 = g0 * us2f(ao4.x) + (1.f - g0) * us2f(xv4.x);
    float v1 = g1 * us2f(ao4.y) + (1.f - g1) * us2f(xv4.y);
    float v2 = g2 * us2f(ao4.z) + (1.f - g2) * us2f(xv4.z);
    float v3 = g3 * us2f(ao4.w) + (1.f - g3) * us2f(xv4.w);
    float s  = v0 + v1 + v2 + v3;
    float sq = v0*v0 + v1*v1 + v2*v2 + v3*v3;
    #pragma unroll
    for (int o = 32; o >= 1; o >>= 1) { s += __shfl_xor(s, o); sq += __shfl_xor(sq, o); }
    const float mean = s * (1.0f / 256.0f);
    const float var  = sq * (1.0f / 256.0f) - mean * mean;
    const float rs = rsqrtf(var + 1e-5f);
    const float4 gv = *(const float4*)(g + lane * 4);
    const float4 bv = *(const float4*)(bta + lane * 4);
    bf16 ov[4] = { f2b((v0 - mean) * rs * gv.x + bv.x), f2b((v1 - mean) * rs * gv.y + bv.y),
                   f2b((v2 - mean) * rs * gv.z + bv.z), f2b((v3 - mean) * rs * gv.w + bv.w) };
    *(ushort4*)(valid + (size_t)node * 256 + lane * 4) = *(const ushort4*)ov;
}

// ---------------- confidence layer2 + weighted (wave per node) ----------------
__global__ __launch_bounds__(256) void conf_w_k(
    const bf16* __restrict__ t1, const float* __restrict__ Wc2, const float* __restrict__ bc2,
    const bf16* __restrict__ valid, float* __restrict__ conf, bf16* __restrict__ cat2)
{
    const int node = blockIdx.x * 4 + (threadIdx.x >> 6);
    const int lane = threadIdx.x & 63;
    float a = b2f(t1[(size_t)node * 128 + lane]) * Wc2[lane]
            + b2f(t1[(size_t)node * 128 + 64 + lane]) * Wc2[64 + lane];
    #pragma unroll
    for (int o = 32; o >= 1; o >>= 1) a += __shfl_xor(a, o);
    const float c = 1.0f / (1.0f + __expf(-(a + bc2[0])));
    if (lane == 0) conf[node] = c;
    const ushort4 vv = *(const ushort4*)(valid + (size_t)node * 256 + lane * 4);
    bf16 ov[4] = { f2b(us2f(vv.x) * c), f2b(us2f(vv.y) * c), f2b(us2f(vv.z) * c), f2b(us2f(vv.w) * c) };
    *(ushort4*)(cat2 + (size_t)node * 512 + 256 + lane * 4) = *(const ushort4*)ov;
}

// ---------------- CSR8 build: counts, hierarchical scan, fill ----------------
__global__ __launch_bounds__(256) void count8_k(
    const int* __restrict__ dst, const int* __restrict__ et, int* __restrict__ cnt8)
{
    const int e = blockIdx.x * 256 + threadIdx.x;
    if (e < E_) atomicAdd(&cnt8[dst[e] * 8 + et[e]], 1);
}

// stage A: per-block (256-elem) totals of cnt8[131072] -> bsum[512]
__global__ __launch_bounds__(256) void scanA_k(
    const int* __restrict__ cnt8, int* __restrict__ bsum)
{
    __shared__ int red[256];
    const int tid = threadIdx.x;
    red[tid] = cnt8[blockIdx.x * 256 + tid];
    __syncthreads();
    for (int s = 128; s > 0; s >>= 1) { if (tid < s) red[tid] += red[tid + s]; __syncthreads(); }
    if (tid == 0) bsum[blockIdx.x] = red[0];
}

// stage B: 1 block, exclusive scan of bsum[512] -> boff[512]
__global__ __launch_bounds__(256) void scanB_k(
    const int* __restrict__ bsum, int* __restrict__ boff)
{
    __shared__ int part[256];
    const int tid = threadIdx.x;
    const int v0 = bsum[tid * 2], v1 = bsum[tid * 2 + 1];
    part[tid] = v0 + v1;
    __syncthreads();
    for (int off = 1; off < 256; off <<= 1) {
        int t = (tid >= off) ? part[tid - off] : 0;
        __syncthreads();
        part[tid] += t;
        __syncthreads();
    }
    const int base = (tid == 0) ? 0 : part[tid - 1];
    boff[tid * 2] = base;
    boff[tid * 2 + 1] = base + v0;
}

// stage C: per-block local exclusive scan + global offset -> rowptr8, cursor8
__global__ __launch_bounds__(256) void scanC_k(
    const int* __restrict__ cnt8, const int* __restrict__ boff,
    int* __restrict__ rowptr8, int* __restrict__ cursor8)
{
    __shared__ int part[256];
    const int tid = threadIdx.x;
    const int gbase = blockIdx.x * 256;
    const int v = cnt8[gbase + tid];
    part[tid] = v;
    __syncthreads();
    for (int off = 1; off < 256; off <<= 1) {
        int t = (tid >= off) ? part[tid - off] : 0;
        __syncthreads();
        part[tid] += t;
        __syncthreads();
    }
    const int excl = part[tid] - v + boff[blockIdx.x];
    rowptr8[gbase + tid] = excl;
    cursor8[gbase + tid] = excl;
    if (blockIdx.x == 511 && tid == 255) rowptr8[BN_ * 8] = excl + v;
}

__global__ __launch_bounds__(256) void fill8_k(
    const int* __restrict__ src, const int* __restrict__ dst, const int* __restrict__ et,
    int* __restrict__ cursor8, int* __restrict__ elist)
{
    const int e = blockIdx.x * 256 + threadIdx.x;
    if (e < E_) {
        const int pos = atomicAdd(&cursor8[dst[e] * 8 + et[e]], 1);
        elist[pos] = src[e];
    }
}

// ---------------- RGCN aggregate-first: S[node] = [mean_r xn rows (8x256) | xn row] ----------------
__global__ __launch_bounds__(256) void gather_sum_k(
    const int* __restrict__ rowptr8, const int* __restrict__ elist,
    const bf16* __restrict__ xn, bf16* __restrict__ S)
{
    const int node = blockIdx.x * 4 + (threadIdx.x >> 6);
    const int lane = threadIdx.x & 63;
    bf16* Srow = S + (size_t)node * 2304;
    *(ushort4*)(Srow + 2048 + lane * 4) = *(const ushort4*)(xn + (size_t)node * 256 + lane * 4);
    const int base = node * 8;
    #pragma unroll
    for (int r = 0; r < 8; ++r) {
        const int e0 = rowptr8[base + r], e1 = rowptr8[base + r + 1];
        float a0 = 0.f, a1 = 0.f, a2 = 0.f, a3 = 0.f;
        int e = e0;
        for (; e + 1 < e1; e += 2) {
            const int s0 = elist[e], s1 = elist[e + 1];
            const ushort4 h0 = *(const ushort4*)(xn + (size_t)s0 * 256 + lane * 4);
            const ushort4 h1 = *(const ushort4*)(xn + (size_t)s1 * 256 + lane * 4);
            a0 += us2f(h0.x) + us2f(h1.x);
            a1 += us2f(h0.y) + us2f(h1.y);
            a2 += us2f(h0.z) + us2f(h1.z);
            a3 += us2f(h0.w) + us2f(h1.w);
        }
        if (e < e1) {
            const ushort4 hv = *(const ushort4*)(xn + (size_t)elist[e] * 256 + lane * 4);
            a0 += us2f(hv.x); a1 += us2f(hv.y); a2 += us2f(hv.z); a3 += us2f(hv.w);
        }
        const float inv = 1.0f / fmaxf((float)(e1 - e0), 1.0f);
        bf16 ov[4] = { f2b(a0 * inv), f2b(a1 * inv), f2b(a2 * inv), f2b(a3 * inv) };
        *(ushort4*)(Srow + r * 256 + lane * 4) = *(const ushort4*)ov;
    }
}

// ---------------- pooling stage 1 ----------------
__global__ __launch_bounds__(256) void pool1_k(
    const bf16* __restrict__ xr, const float* __restrict__ conf, float* __restrict__ partial)
{
    const int b = blockIdx.x, chunk = blockIdx.y, c = threadIdx.x;
    float acc = 0.0f;
    for (int n = 0; n < 64; ++n) {
        const int node = b * 1024 + chunk * 64 + n;
        acc += conf[node] * b2f(xr[(size_t)node * 256 + c]);
    }
    partial[(size_t)(b * 16 + chunk) * 256 + c] = acc;
}

// ---------------- pooling stage 2 + head ----------------
__global__ __launch_bounds__(256) void pool2_k(
    const float* __restrict__ partial, const float* __restrict__ conf,
    const float* __restrict__ Wh, const float* __restrict__ bh, float* __restrict__ out)
{
    const int b = blockIdx.x, tid = threadIdx.x;
    __shared__ float red[256];
    __shared__ float pooled[256];
    float pc = 0.0f;
    for (int ch = 0; ch < 16; ++ch) pc += partial[(size_t)(b * 16 + ch) * 256 + tid];
    float s = conf[b * 1024 + tid] + conf[b * 1024 + 256 + tid]
            + conf[b * 1024 + 512 + tid] + conf[b * 1024 + 768 + tid];
    red[tid] = s; __syncthreads();
    for (int st = 128; st > 0; st >>= 1) { if (tid < st) red[tid] += red[tid + st]; __syncthreads(); }
    const float denom = fmaxf(red[0], 1e-8f);
    pooled[tid] = pc / denom;
    __syncthreads();
    if (tid < NS_) {
        float o = bh[tid];
        for (int c = 0; c < 256; ++c) o += pooled[c] * Wh[c * NS_ + tid];
        out[b * NS_ + tid] = o;
    }
}

extern "C" void kernel_launch(void* const* d_in, const int* in_sizes, int n_in,
                              void* d_out, int out_size, void* d_ws, size_t ws_size,
                              hipStream_t stream) {
    const float* x    = (const float*)d_in[0];
    const int*   ei   = (const int*)d_in[1];
    const int*   et   = (const int*)d_in[2];
    const float* Wq   = (const float*)d_in[3];  const float* bq  = (const float*)d_in[4];
    const float* Wk   = (const float*)d_in[5];  const float* bk  = (const float*)d_in[6];
    const float* Wv   = (const float*)d_in[7];  const float* bv  = (const float*)d_in[8];
    const float* Wg   = (const float*)d_in[9];  const float* bg  = (const float*)d_in[10];
    const float* lag  = (const float*)d_in[11]; const float* lab = (const float*)d_in[12];
    const float* Wc1  = (const float*)d_in[13]; const float* bc1 = (const float*)d_in[14];
    const float* Wc2  = (const float*)d_in[15]; const float* bc2 = (const float*)d_in[16];
    const float* Wm   = (const float*)d_in[17]; const float* bm  = (const float*)d_in[18];
    const float* l1g  = (const float*)d_in[19]; const float* l1b = (const float*)d_in[20];
    const float* Wrel = (const float*)d_in[21]; const float* Wroot = (const float*)d_in[22];
    const float* brg  = (const float*)d_in[23];
    const float* l2g  = (const float*)d_in[24]; const float* l2b = (const float*)d_in[25];
    const float* Wh   = (const float*)d_in[26]; const float* bh  = (const float*)d_in[27];
    const int* esrc = ei;
    const int* edst = ei + E_;

    char* w8 = (char*)d_ws;
    bf16*  qkv   = (bf16*)(w8 + 0);            // [16384,768]
    bf16*  Sbig  = (bf16*)(w8 + 0);            // [16384,2304] 75.5 MB (qkv/sP/cat1 dead by then)
    bf16*  sP    = (bf16*)(w8 + 25165824);     // [16x1024x1024]
    bf16*  cat1  = (bf16*)(w8 + 58720256);     // [aout|xb] ld 512
    bf16*  cat2  = (bf16*)(w8 + 75497472);     // [xb|weighted] ld 512
    bf16*  gate  = (bf16*)(w8 + 92274688);     // 8 MB; reused as aggb after blend
    bf16*  valid = (bf16*)(w8 + 100663296);
    bf16*  t1    = (bf16*)(w8 + 109051904);
    bf16*  xm    = (bf16*)(w8 + 113246208);
    bf16*  xb    = (bf16*)(w8 + 121634816);
    bf16*  xn    = (bf16*)(w8 + 130023424);
    bf16*  vtb   = (bf16*)(w8 + 138412032);
    bf16*  xr    = (bf16*)(w8 + 146800640);
    float* conf  = (float*)(w8 + 155189248);
    float* part  = (float*)(w8 + 155254784);
    bf16*  WT    = (bf16*)(w8 + 155516928);    // 2,162,688 B -> ends 157,679,616
    int*  cnt8i   = (int*)(w8 + 157679616);    // 524,288 B   -> ends 158,203,904
    int*  rowptr8 = (int*)(w8 + 158203904);    // 524,292 B (+pad) -> cursor8 @ +524,544
    int*  cursor8 = (int*)(w8 + 158728448);    // 524,288 B   -> ends 159,252,736
    int*  elist   = (int*)(w8 + 159252736);    // 1,048,576 B -> ends 160,301,312
    int*  bsum    = (int*)(w8 + 160301312);    // 2,048 B
    int*  boff    = (int*)(w8 + 160303360);    // 2,048 B
    bf16* WqkvT = WT;                  // [768,256]
    bf16* WgT   = WT + 196608;         // [256,512]
    bf16* WmT   = WT + 327680;         // [256,512]
    bf16* Wc1T  = WT + 458752;         // [128,256]
    bf16* WB2   = WT + 491520;         // [256,2304]
    bf16* aggb  = gate;                // agg bf16 (gate dead after blend)
    float* outp = (float*)d_out;

    dim3 blk(256);

    // --- prep: weights, x conversion, CSR8 build (hierarchical scan) ---
    prep_w_k<<<1056, blk, 0, stream>>>(Wq, Wk, Wv, Wg, Wm, Wc1, Wrel, Wroot, WT);
    cvt_x_k<<<BNC_ / 1024, blk, 0, stream>>>(x, xb, cat1, cat2);
    hipMemsetAsync(cnt8i, 0, (size_t)BN_ * 8 * sizeof(int), stream);
    count8_k<<<E_ / 256, blk, 0, stream>>>(edst, et, cnt8i);
    scanA_k<<<512, blk, 0, stream>>>(cnt8i, bsum);
    scanB_k<<<1, blk, 0, stream>>>(bsum, boff);
    scanC_k<<<512, blk, 0, stream>>>(cnt8i, boff, rowptr8, cursor8);
    fill8_k<<<E_ / 256, blk, 0, stream>>>(esrc, edst, et, cursor8, elist);

    // --- fused QKV projection: qkv[16384,768] ---
    gemm_bf16<0><<<dim3(6, 128, 1), blk, 0, stream>>>(
        xb, 256, 0, WqkvT, 256, 0, qkv, 768, 0, bq, bk, bv, 256);
    vtrans_k<<<dim3(8, 32, 16), blk, 0, stream>>>(qkv, vtb);

    // --- attention: QK^T (64-tile depth-4, 4096 blocks), softmax, PV (128-tile) ---
    gemm64_bf16<0><<<dim3(16, 16, 16), blk, 0, stream>>>(
        qkv, 768, 786432, qkv + 256, 768, 786432, sP, 1024, 1048576, nullptr, 256);
    softmax_k<<<BN_, blk, 0, stream>>>(sP);
    gemm_bf16<0><<<dim3(2, 8, 16), blk, 0, stream>>>(
        sP, 1024, 1048576, vtb, 1024, 262144, cat1, 512, 524288, nullptr, nullptr, nullptr, 1024);

    // --- gate (64-tile depth-4), blend+LN ---
    gemm64_bf16<2><<<dim3(4, 256, 1), blk, 0, stream>>>(
        cat1, 512, 0, WgT, 512, 0, gate, 256, 0, bg, 512);
    blend_ln_k<<<BN_ / 4, blk, 0, stream>>>(gate, cat1, xb, valid, lag, lab);

    // --- confidence (64-tile depth-4) + weighted ---
    gemm64_bf16<1><<<dim3(2, 256, 1), blk, 0, stream>>>(
        valid, 256, 0, Wc1T, 256, 0, t1, 128, 0, bc1, 256);
    conf_w_k<<<BN_ / 4, blk, 0, stream>>>(t1, Wc2, bc2, valid, conf, cat2);

    // --- mixer (64-tile depth-4) + LN1 ---
    gemm64_bf16<1><<<dim3(4, 256, 1), blk, 0, stream>>>(
        cat2, 512, 0, WmT, 512, 0, xm, 256, 0, bm, 512);
    ln_k<0><<<BN_ / 4, blk, 0, stream>>>(xm, xn, l1g, l1b);

    // --- RGCN aggregate-first: gather-mean from hot xn, then ONE long-K GEMM ---
    gather_sum_k<<<BN_ / 4, blk, 0, stream>>>(rowptr8, elist, xn, Sbig);
    gemm_bf16<0><<<dim3(2, 128, 1), blk, 0, stream>>>(
        Sbig, 2304, 0, WB2, 2304, 0, aggb, 256, 0, brg, nullptr, nullptr, 2304);
    ln_k<1><<<BN_ / 4, blk, 0, stream>>>(aggb, xr, l2g, l2b);

    // --- pool + head ---
    pool1_k<<<dim3(B_, 16), blk, 0, stream>>>(xr, conf, part);
    pool2_k<<<B_, blk, 0, stream>>>(part, conf, Wh, bh, outp);
}

// Round 17
// 258.238 us; speedup vs baseline: 1.2519x; 1.0033x over previous
//
#include <hip/hip_runtime.h>
#include <hip/hip_bf16.h>

#define B_ 16
#define N_ 1024
#define C_ 256
#define R_ 8
#define E_ 262144
#define NS_ 32
#define BN_ (B_*N_)
#define BNC_ (BN_*C_)

typedef __hip_bfloat16 bf16;
typedef __attribute__((ext_vector_type(4))) float f32x4;
typedef __attribute__((ext_vector_type(8))) short bf16x8;

__device__ __forceinline__ float b2f(bf16 x) { return __bfloat162float(x); }
__device__ __forceinline__ bf16  f2b(float x) { return __float2bfloat16(x); }
__device__ __forceinline__ float us2f(unsigned short u) { return __uint_as_float((unsigned)u << 16); }

// async global->LDS, 16B per lane (wave-uniform LDS base + lane*16 implicit)
__device__ __forceinline__ void gload16(const void* g, void* l) {
    auto gp = (const __attribute__((address_space(1))) void*)(unsigned long long)g;
    auto lp = (__attribute__((address_space(3))) void*)(unsigned)(unsigned long long)l;
    __builtin_amdgcn_global_load_lds(gp, lp, 16, 0, 0);
}

// ---------------- bf16 MFMA GEMM (128x128 tile): C = act(A @ B^T + bias) ----------------
// Depth-3 pipeline (48 KB LDS), vmcnt ladder 8/4/0; XOR slot swizzle both sides;
// XCD-aware block swizzle (bijective when nwg % 8 == 0).
template<int ACT>
__global__ __launch_bounds__(256) void gemm_bf16(
    const bf16* __restrict__ A, int lda, long long sA,
    const bf16* __restrict__ Bm, int ldb, long long sB,
    bf16* __restrict__ Cc, int ldc, long long sC,
    const float* __restrict__ bias, const float* __restrict__ bias2,
    const float* __restrict__ bias3, int K)
{
    __shared__ short sbuf[24576];        // 48 KB
    const int tid = threadIdx.x;
    const int lane = tid & 63, w = tid >> 6;
    const int wr = w >> 1, wc = w & 1;

    const int gx = gridDim.x;
    const int nwg = gx * gridDim.y;
    int id = blockIdx.y * gx + blockIdx.x;
    if ((nwg & 7) == 0) { const int cpx = nwg >> 3; id = (id & 7) * cpx + (id >> 3); }
    const int bm = (id / gx) * 128, bn = (id % gx) * 128;

    const bf16* Ab = A + (size_t)blockIdx.z * sA;
    const bf16* Bb = Bm + (size_t)blockIdx.z * sB;
    bf16* Cb = Cc + (size_t)blockIdx.z * sC;

    const int rg = lane >> 2;
    const int kswz = ((lane & 3) ^ ((rg >> 1) & 3)) * 8;

    f32x4 acc[4][4];
    const f32x4 zz = {0.f, 0.f, 0.f, 0.f};
    #pragma unroll
    for (int i = 0; i < 4; ++i)
        #pragma unroll
        for (int j = 0; j < 4; ++j) acc[i][j] = zz;

    const int fr = lane & 15;
    const int fm = lane >> 4;
    const int fslot = (fm ^ ((fr >> 1) & 3)) * 8;

    const int NI = K >> 5;

#define STAGE_AB(bi, kk) do {                                                          \
    _Pragma("unroll")                                                                  \
    for (int t_ = 0; t_ < 2; ++t_) {                                                   \
        gload16(Ab + (size_t)(bm + t_*64 + w*16 + rg) * lda + (kk) + kswz,             \
                sbuf + (bi)*4096 + t_*2048 + w*512);                                   \
        gload16(Bb + (size_t)(bn + t_*64 + w*16 + rg) * ldb + (kk) + kswz,             \
                sbuf + 12288 + (bi)*4096 + t_*2048 + w*512);                           \
    } } while (0)

    STAGE_AB(0, 0);
    if (NI > 1) STAGE_AB(1, 32);
    if (NI > 2) STAGE_AB(2, 64);

    int cur = 0;
    for (int i = 0; i < NI; ++i) {
        if (i + 2 < NI)      asm volatile("s_waitcnt vmcnt(8)" ::: "memory");
        else if (i + 1 < NI) asm volatile("s_waitcnt vmcnt(4)" ::: "memory");
        else                 asm volatile("s_waitcnt vmcnt(0)" ::: "memory");
        __builtin_amdgcn_s_barrier();
        __builtin_amdgcn_sched_barrier(0);

        bf16x8 af[4], bfr[4];
        const short* Ac = sbuf + cur * 4096;
        const short* Bc = sbuf + 12288 + cur * 4096;
        #pragma unroll
        for (int ii = 0; ii < 4; ++ii)
            af[ii] = *(const bf16x8*)&Ac[(wr*64 + ii*16 + fr)*32 + fslot];
        #pragma unroll
        for (int jj = 0; jj < 4; ++jj)
            bfr[jj] = *(const bf16x8*)&Bc[(wc*64 + jj*16 + fr)*32 + fslot];

        asm volatile("s_waitcnt lgkmcnt(0)" ::: "memory");
        __builtin_amdgcn_s_barrier();
        __builtin_amdgcn_sched_barrier(0);
        if (i + 3 < NI) STAGE_AB(cur, (i + 3) * 32);

        #pragma unroll
        for (int ii = 0; ii < 4; ++ii)
            #pragma unroll
            for (int jj = 0; jj < 4; ++jj)
                acc[ii][jj] = __builtin_amdgcn_mfma_f32_16x16x32_bf16(af[ii], bfr[jj], acc[ii][jj], 0, 0, 0);
        cur = (cur == 2) ? 0 : cur + 1;
    }
#undef STAGE_AB

    __syncthreads();
    const int er = (lane >> 4) * 4, ec = lane & 15;
    #pragma unroll
    for (int half = 0; half < 2; ++half) {
        if (wr == half) {
            #pragma unroll
            for (int j = 0; j < 4; ++j) {
                const int col = bn + wc*64 + j*16 + ec;
                float bvv = 0.0f;
                if (bias) {
                    const int seg = col >> 8;
                    const float* bp = (seg == 0) ? bias : (seg == 1 ? bias2 : bias3);
                    bvv = bp[col & 255];
                }
                #pragma unroll
                for (int i = 0; i < 4; ++i) {
                    #pragma unroll
                    for (int p = 0; p < 4; ++p) {
                        float val = acc[i][j][p] + bvv;
                        if (ACT == 1) val = fmaxf(val, 0.0f);
                        if (ACT == 2) val = 1.0f / (1.0f + __expf(-val));
                        *(bf16*)&sbuf[(i*16 + er + p)*136 + wc*64 + j*16 + ec] = f2b(val);
                    }
                }
            }
        }
        __syncthreads();
        #pragma unroll
        for (int it = 0; it < 4; ++it) {
            const int ch = tid + it*256;
            const int row = ch >> 4, cp = (ch & 15) * 8;
            *(bf16x8*)&Cb[(size_t)(bm + half*64 + row) * ldc + bn + cp] =
                *(const bf16x8*)&sbuf[row*136 + cp];
        }
        __syncthreads();
    }
}

// ---------------- split-K fp32-partial GEMM (128x128 tile, depth-3) ----------------
// z = K-split index; computes A[:, z*Kc : (z+1)*Kc] @ B^T chunk into
// Cf + z*BNC (fp32, ldc 256). For the RGCN long-K GEMM (adds blocks/CU).
__global__ __launch_bounds__(256) void gemm_splitk(
    const bf16* __restrict__ A, int lda,
    const bf16* __restrict__ Bm, int ldb,
    float* __restrict__ Cf, int Kc)
{
    __shared__ short sbuf[24576];        // 48 KB; epilogue reuses as float[64][132]
    const int tid = threadIdx.x;
    const int lane = tid & 63, w = tid >> 6;
    const int wr = w >> 1, wc = w & 1;

    const int gx = gridDim.x;
    const int nwg = gx * gridDim.y;
    int id = blockIdx.y * gx + blockIdx.x;
    if ((nwg & 7) == 0) { const int cpx = nwg >> 3; id = (id & 7) * cpx + (id >> 3); }
    const int bm = (id / gx) * 128, bn = (id % gx) * 128;

    const bf16* Ab = A + (size_t)blockIdx.z * Kc;
    const bf16* Bb = Bm + (size_t)blockIdx.z * Kc;
    float* Cb = Cf + (size_t)blockIdx.z * BNC_;

    const int rg = lane >> 2;
    const int kswz = ((lane & 3) ^ ((rg >> 1) & 3)) * 8;

    f32x4 acc[4][4];
    const f32x4 zz = {0.f, 0.f, 0.f, 0.f};
    #pragma unroll
    for (int i = 0; i < 4; ++i)
        #pragma unroll
        for (int j = 0; j < 4; ++j) acc[i][j] = zz;

    const int fr = lane & 15;
    const int fm = lane >> 4;
    const int fslot = (fm ^ ((fr >> 1) & 3)) * 8;

    const int NI = Kc >> 5;

#define STAGE_AB(bi, kk) do {                                                          \
    _Pragma("unroll")                                                                  \
    for (int t_ = 0; t_ < 2; ++t_) {                                                   \
        gload16(Ab + (size_t)(bm + t_*64 + w*16 + rg) * lda + (kk) + kswz,             \
                sbuf + (bi)*4096 + t_*2048 + w*512);                                   \
        gload16(Bb + (size_t)(bn + t_*64 + w*16 + rg) * ldb + (kk) + kswz,             \
                sbuf + 12288 + (bi)*4096 + t_*2048 + w*512);                           \
    } } while (0)

    STAGE_AB(0, 0);
    if (NI > 1) STAGE_AB(1, 32);
    if (NI > 2) STAGE_AB(2, 64);

    int cur = 0;
    for (int i = 0; i < NI; ++i) {
        if (i + 2 < NI)      asm volatile("s_waitcnt vmcnt(8)" ::: "memory");
        else if (i + 1 < NI) asm volatile("s_waitcnt vmcnt(4)" ::: "memory");
        else                 asm volatile("s_waitcnt vmcnt(0)" ::: "memory");
        __builtin_amdgcn_s_barrier();
        __builtin_amdgcn_sched_barrier(0);

        bf16x8 af[4], bfr[4];
        const short* Ac = sbuf + cur * 4096;
        const short* Bc = sbuf + 12288 + cur * 4096;
        #pragma unroll
        for (int ii = 0; ii < 4; ++ii)
            af[ii] = *(const bf16x8*)&Ac[(wr*64 + ii*16 + fr)*32 + fslot];
        #pragma unroll
        for (int jj = 0; jj < 4; ++jj)
            bfr[jj] = *(const bf16x8*)&Bc[(wc*64 + jj*16 + fr)*32 + fslot];

        asm volatile("s_waitcnt lgkmcnt(0)" ::: "memory");
        __builtin_amdgcn_s_barrier();
        __builtin_amdgcn_sched_barrier(0);
        if (i + 3 < NI) STAGE_AB(cur, (i + 3) * 32);

        #pragma unroll
        for (int ii = 0; ii < 4; ++ii)
            #pragma unroll
            for (int jj = 0; jj < 4; ++jj)
                acc[ii][jj] = __builtin_amdgcn_mfma_f32_16x16x32_bf16(af[ii], bfr[jj], acc[ii][jj], 0, 0, 0);
        cur = (cur == 2) ? 0 : cur + 1;
    }
#undef STAGE_AB

    // fp32 epilogue: two-phase LDS bounce (float [64][132]) -> float4 stores.
    // FIX (r16 bug): store 64 rows x 128 cols per half => 8 its, row=ch>>5, cp=(ch&31)*4.
    __syncthreads();
    float* fbuf = (float*)sbuf;
    const int er = (lane >> 4) * 4, ec = lane & 15;
    #pragma unroll
    for (int half = 0; half < 2; ++half) {
        if (wr == half) {
            #pragma unroll
            for (int j = 0; j < 4; ++j)
                #pragma unroll
                for (int i = 0; i < 4; ++i)
                    #pragma unroll
                    for (int p = 0; p < 4; ++p)
                        fbuf[(i*16 + er + p)*132 + wc*64 + j*16 + ec] = acc[i][j][p];
        }
        __syncthreads();
        #pragma unroll
        for (int it = 0; it < 8; ++it) {
            const int ch = tid + it*256;           // 2048 chunks of 4 floats = 64 rows x 128 cols
            const int row = ch >> 5, cp = (ch & 31) * 4;
            *(float4*)&Cb[(size_t)(bm + half*64 + row) * 256 + bn + cp] =
                *(const float4*)&fbuf[row*132 + cp];
        }
        __syncthreads();
    }
}

// ---------------- bf16 MFMA GEMM (64x64 tile, depth-4 pipeline) ----------------
template<int ACT>
__global__ __launch_bounds__(256) void gemm64_bf16(
    const bf16* __restrict__ A, int lda, long long sA,
    const bf16* __restrict__ Bm, int ldb, long long sB,
    bf16* __restrict__ Cc, int ldc, long long sC,
    const float* __restrict__ bias, int K)
{
    __shared__ short sbuf[16384];        // 32 KB
    const int tid = threadIdx.x;
    const int lane = tid & 63, w = tid >> 6;
    const int wr = w >> 1, wc = w & 1;

    const int gx = gridDim.x;
    const int nwg = gx * gridDim.y;
    int id = blockIdx.y * gx + blockIdx.x;
    if ((nwg & 7) == 0) { const int cpx = nwg >> 3; id = (id & 7) * cpx + (id >> 3); }
    const int bm = (id / gx) * 64, bn = (id % gx) * 64;

    const bf16* Ab = A + (size_t)blockIdx.z * sA;
    const bf16* Bb = Bm + (size_t)blockIdx.z * sB;
    bf16* Cb = Cc + (size_t)blockIdx.z * sC;

    const int rg = lane >> 2;
    const int kswz = ((lane & 3) ^ ((rg >> 1) & 3)) * 8;

    f32x4 acc[2][2];
    const f32x4 zz = {0.f, 0.f, 0.f, 0.f};
    #pragma unroll
    for (int i = 0; i < 2; ++i)
        #pragma unroll
        for (int j = 0; j < 2; ++j) acc[i][j] = zz;

    const int fr = lane & 15;
    const int fm = lane >> 4;
    const int fslot = (fm ^ ((fr >> 1) & 3)) * 8;

    const int NI = K >> 5;

#define STAGE64(bi, kk) do {                                                           \
    gload16(Ab + (size_t)(bm + w*16 + rg) * lda + (kk) + kswz,                         \
            sbuf + (bi)*2048 + w*512);                                                 \
    gload16(Bb + (size_t)(bn + w*16 + rg) * ldb + (kk) + kswz,                         \
            sbuf + 8192 + (bi)*2048 + w*512);                                          \
    } while (0)

    STAGE64(0, 0);
    if (NI > 1) STAGE64(1, 32);
    if (NI > 2) STAGE64(2, 64);
    if (NI > 3) STAGE64(3, 96);

    for (int i = 0; i < NI; ++i) {
        const int cur = i & 3;
        if (i + 3 < NI)      asm volatile("s_waitcnt vmcnt(6)" ::: "memory");
        else if (i + 2 < NI) asm volatile("s_waitcnt vmcnt(4)" ::: "memory");
        else if (i + 1 < NI) asm volatile("s_waitcnt vmcnt(2)" ::: "memory");
        else                 asm volatile("s_waitcnt vmcnt(0)" ::: "memory");
        __builtin_amdgcn_s_barrier();
        __builtin_amdgcn_sched_barrier(0);

        bf16x8 af[2], bfr[2];
        const short* Ac = sbuf + cur * 2048;
        const short* Bc = sbuf + 8192 + cur * 2048;
        #pragma unroll
        for (int ii = 0; ii < 2; ++ii)
            af[ii] = *(const bf16x8*)&Ac[(wr*32 + ii*16 + fr)*32 + fslot];
        #pragma unroll
        for (int jj = 0; jj < 2; ++jj)
            bfr[jj] = *(const bf16x8*)&Bc[(wc*32 + jj*16 + fr)*32 + fslot];

        asm volatile("s_waitcnt lgkmcnt(0)" ::: "memory");
        __builtin_amdgcn_s_barrier();
        __builtin_amdgcn_sched_barrier(0);
        if (i + 4 < NI) STAGE64(cur, (i + 4) * 32);

        #pragma unroll
        for (int ii = 0; ii < 2; ++ii)
            #pragma unroll
            for (int jj = 0; jj < 2; ++jj)
                acc[ii][jj] = __builtin_amdgcn_mfma_f32_16x16x32_bf16(af[ii], bfr[jj], acc[ii][jj], 0, 0, 0);
    }
#undef STAGE64

    __syncthreads();
    const int er = (lane >> 4) * 4, ec = lane & 15;
    #pragma unroll
    for (int j = 0; j < 2; ++j) {
        const int col = bn + wc*32 + j*16 + ec;
        const float bvv = bias ? bias[col & 255] : 0.0f;
        #pragma unroll
        for (int i = 0; i < 2; ++i) {
            #pragma unroll
            for (int p = 0; p < 4; ++p) {
                float val = acc[i][j][p] + bvv;
                if (ACT == 1) val = fmaxf(val, 0.0f);
                if (ACT == 2) val = 1.0f / (1.0f + __expf(-val));
                *(bf16*)&sbuf[(wr*32 + i*16 + er + p)*72 + wc*32 + j*16 + ec] = f2b(val);
            }
        }
    }
    __syncthreads();
    #pragma unroll
    for (int it = 0; it < 2; ++it) {
        const int ch = tid + it*256;
        const int row = ch >> 3, cp = (ch & 7) * 8;
        *(bf16x8*)&Cb[(size_t)(bm + row) * ldc + bn + cp] =
            *(const bf16x8*)&sbuf[row*72 + cp];
    }
}

// ---------------- weight prep: transposes to bf16, one dispatch ----------------
__global__ __launch_bounds__(256) void prep_w_k(
    const float* __restrict__ Wq, const float* __restrict__ Wk, const float* __restrict__ Wv,
    const float* __restrict__ Wg, const float* __restrict__ Wm, const float* __restrict__ Wc1,
    const float* __restrict__ Wrel, const float* __restrict__ Wroot, bf16* __restrict__ WT)
{
    int t = blockIdx.x;
    const float* in; bf16* out; int Nn, ldout, kofs;
    if (t < 192)      { int wsel = t >> 6; t &= 63;
                        in = wsel == 0 ? Wq : (wsel == 1 ? Wk : Wv);
                        out = WT + wsel*65536; Nn = 256; ldout = 256; kofs = 0; }
    else if (t < 320) { t -= 192; in = Wg;  out = WT + 196608; Nn = 256; ldout = 512; kofs = 0; }
    else if (t < 448) { t -= 320; in = Wm;  out = WT + 327680; Nn = 256; ldout = 512; kofs = 0; }
    else if (t < 480) { t -= 448; in = Wc1; out = WT + 458752; Nn = 128; ldout = 256; kofs = 0; }
    else if (t < 992) { t -= 480; int r = t >> 6; t &= 63;
                        in = Wrel + (size_t)r*65536; out = WT + 491520; Nn = 256; ldout = 2304; kofs = r*256; }
    else              { t -= 992; in = Wroot; out = WT + 491520; Nn = 256; ldout = 2304; kofs = 2048; }
    const int tpr = Nn >> 5;
    const int n0 = (t % tpr) * 32, k0 = (t / tpr) * 32;
    __shared__ float tile[32][33];
    const int tx = threadIdx.x & 31, ty = threadIdx.x >> 5;
    #pragma unroll
    for (int i = 0; i < 4; ++i) {
        int r = ty + i*8;
        tile[r][tx] = in[(size_t)(k0 + r) * Nn + n0 + tx];
    }
    __syncthreads();
    #pragma unroll
    for (int i = 0; i < 4; ++i) {
        int r = ty + i*8;
        out[(size_t)(n0 + r) * ldout + kofs + k0 + tx] = f2b(tile[tx][r]);
    }
}

// ---------------- V^T: qkv V-part [1024,256] (ld 768) -> vtb [256,1024] per batch ----------------
__global__ __launch_bounds__(256) void vtrans_k(
    const bf16* __restrict__ in, bf16* __restrict__ out)
{
    __shared__ float tile[32][33];
    in  += (size_t)blockIdx.z * 786432 + 512;
    out += (size_t)blockIdx.z * 262144;
    const int n0 = blockIdx.x * 32, k0 = blockIdx.y * 32;
    const int tx = threadIdx.x & 31, ty = threadIdx.x >> 5;
    #pragma unroll
    for (int i = 0; i < 4; ++i) {
        int r = ty + i*8;
        tile[r][tx] = b2f(in[(size_t)(k0 + r) * 768 + n0 + tx]);
    }
    __syncthreads();
    #pragma unroll
    for (int i = 0; i < 4; ++i) {
        int r = ty + i*8;
        out[(size_t)(n0 + r) * 1024 + k0 + tx] = f2b(tile[tx][r]);
    }
}

// ---------------- x fp32 -> bf16 (xb, cat1 right half, cat2 left half) ----------------
__global__ __launch_bounds__(256) void cvt_x_k(const float* __restrict__ x,
    bf16* __restrict__ xb, bf16* __restrict__ cat1, bf16* __restrict__ cat2)
{
    const int i4 = (blockIdx.x * 256 + threadIdx.x) * 4;
    const float4 xv = *(const float4*)(x + i4);
    bf16 bv[4] = { f2b(xv.x), f2b(xv.y), f2b(xv.z), f2b(xv.w) };
    const ushort4 pack = *(const ushort4*)bv;
    const int row = i4 >> 8, col = i4 & 255;
    *(ushort4*)(xb + i4) = pack;
    *(ushort4*)(cat1 + (size_t)row * 512 + 256 + col) = pack;
    *(ushort4*)(cat2 + (size_t)row * 512 + col) = pack;
}

// ---------------- row softmax over 1024 bf16 scores in place (pre-scale 1/16) ----------------
__global__ __launch_bounds__(256) void softmax_k(bf16* __restrict__ s)
{
    const int row = blockIdx.x, tid = threadIdx.x;
    const int lane = tid & 63, wid = tid >> 6;
    bf16* rp = s + (size_t)row * 1024 + tid * 4;
    __shared__ float red[8];
    const ushort4 sv = *(const ushort4*)rp;
    float v0 = us2f(sv.x) * 0.0625f, v1 = us2f(sv.y) * 0.0625f;
    float v2 = us2f(sv.z) * 0.0625f, v3 = us2f(sv.w) * 0.0625f;
    float m = fmaxf(fmaxf(v0, v1), fmaxf(v2, v3));
    #pragma unroll
    for (int o = 32; o >= 1; o >>= 1) m = fmaxf(m, __shfl_xor(m, o));
    if (lane == 0) red[wid] = m;
    __syncthreads();
    const float mx = fmaxf(fmaxf(red[0], red[1]), fmaxf(red[2], red[3]));
    float e0 = __expf(v0 - mx), e1 = __expf(v1 - mx), e2 = __expf(v2 - mx), e3 = __expf(v3 - mx);
    float sm = e0 + e1 + e2 + e3;
    #pragma unroll
    for (int o = 32; o >= 1; o >>= 1) sm += __shfl_xor(sm, o);
    if (lane == 0) red[4 + wid] = sm;
    __syncthreads();
    const float inv = 1.0f / (red[4] + red[5] + red[6] + red[7]);
    bf16 ov[4] = { f2b(e0 * inv), f2b(e1 * inv), f2b(e2 * inv), f2b(e3 * inv) };
    *(ushort4*)rp = *(const ushort4*)ov;
}

// ---------------- LN over C=256 (wave per row, 4 ch/lane), bf16 in/out ----------------
template<int RELU>
__global__ __launch_bounds__(256) void ln_k(
    const bf16* __restrict__ in, bf16* __restrict__ out,
    const float* __restrict__ g, const float* __restrict__ bta)
{
    const int node = blockIdx.x * 4 + (threadIdx.x >> 6);
    const int lane = threadIdx.x & 63;
    const ushort4 iv = *(const ushort4*)(in + (size_t)node * 256 + lane * 4);
    float v0 = us2f(iv.x), v1 = us2f(iv.y), v2 = us2f(iv.z), v3 = us2f(iv.w);
    float s  = v0 + v1 + v2 + v3;
    float sq = v0*v0 + v1*v1 + v2*v2 + v3*v3;
    #pragma unroll
    for (int o = 32; o >= 1; o >>= 1) { s += __shfl_xor(s, o); sq += __shfl_xor(sq, o); }
    const float mean = s * (1.0f / 256.0f);
    const float var  = sq * (1.0f / 256.0f) - mean * mean;
    const float rs = rsqrtf(var + 1e-5f);
    const float4 gv = *(const float4*)(g + lane * 4);
    const float4 bv = *(const float4*)(bta + lane * 4);
    float y0 = (v0 - mean) * rs * gv.x + bv.x;
    float y1 = (v1 - mean) * rs * gv.y + bv.y;
    float y2 = (v2 - mean) * rs * gv.z + bv.z;
    float y3 = (v3 - mean) * rs * gv.w + bv.w;
    if (RELU) { y0 = fmaxf(y0, 0.f); y1 = fmaxf(y1, 0.f); y2 = fmaxf(y2, 0.f); y3 = fmaxf(y3, 0.f); }
    bf16 ov[4] = { f2b(y0), f2b(y1), f2b(y2), f2b(y3) };
    *(ushort4*)(out + (size_t)node * 256 + lane * 4) = *(const ushort4*)ov;
}

// ---------------- split-K reduce + brg + LN2 + relu (wave per node) ----------------
__global__ __launch_bounds__(256) void redln_k(
    const float* __restrict__ p0, const float* __restrict__ p1,
    const float* __restrict__ brg,
    const float* __restrict__ g, const float* __restrict__ bta,
    bf16* __restrict__ xr)
{
    const int node = blockIdx.x * 4 + (threadIdx.x >> 6);
    const int lane = threadIdx.x & 63;
    const float4 a = *(const float4*)(p0 + (size_t)node * 256 + lane * 4);
    const float4 b = *(const float4*)(p1 + (size_t)node * 256 + lane * 4);
    const float4 bg4 = *(const float4*)(brg + lane * 4);
    const float v0 = a.x + b.x + bg4.x, v1 = a.y + b.y + bg4.y;
    const float v2 = a.z + b.z + bg4.z, v3 = a.w + b.w + bg4.w;
    float s  = v0 + v1 + v2 + v3;
    float sq = v0*v0 + v1*v1 + v2*v2 + v3*v3;
    #pragma unroll
    for (int m = 32; m >= 1; m >>= 1) { s += __shfl_xor(s, m); sq += __shfl_xor(sq, m); }
    const float mean = s * (1.0f / 256.0f);
    const float var  = sq * (1.0f / 256.0f) - mean * mean;
    const float rs = rsqrtf(var + 1e-5f);
    const float4 gv = *(const float4*)(g + lane * 4);
    const float4 bv = *(const float4*)(bta + lane * 4);
    bf16 tb[4] = { f2b(fmaxf((v0 - mean) * rs * gv.x + bv.x, 0.f)),
                   f2b(fmaxf((v1 - mean) * rs * gv.y + bv.y, 0.f)),
                   f2b(fmaxf((v2 - mean) * rs * gv.z + bv.z, 0.f)),
                   f2b(fmaxf((v3 - mean) * rs * gv.w + bv.w, 0.f)) };
    *(ushort4*)(xr + (size_t)node * 256 + lane * 4) = *(const ushort4*)tb;
}

// ---------------- gated blend + LN (wave per row; residual from bf16 xb) ----------------
__global__ __launch_bounds__(256) void blend_ln_k(
    const bf16* __restrict__ gate, const bf16* __restrict__ cat1,
    const bf16* __restrict__ xb, bf16* __restrict__ valid,
    const float* __restrict__ g, const float* __restrict__ bta)
{
    const int node = blockIdx.x * 4 + (threadIdx.x >> 6);
    const int lane = threadIdx.x & 63;
    const ushort4 gt4 = *(const ushort4*)(gate + (size_t)node * 256 + lane * 4);
    const ushort4 ao4 = *(const ushort4*)(cat1 + (size_t)node * 512 + lane * 4);
    const ushort4 xv4 = *(const ushort4*)(xb + (size_t)node * 256 + lane * 4);
    float g0 = us2f(gt4.x), g1 = us2f(gt4.y), g2 = us2f(gt4.z), g3 = us2f(gt4.w);
    float v0 = g0 * us2f(ao4.x) + (1.f - g0) * us2f(xv4.x);
    float v1 = g1 * us2f(ao4.y) + (1.f - g1) * us2f(xv4.y);
    float v2 = g2 * us2f(ao4.z) + (1.f - g2) * us2f(xv4.z);
    float v3 = g3 * us2f(ao4.w) + (1.f - g3) * us2f(xv4.w);
    float s  = v0 + v1 + v2 + v3;
    float sq = v0*v0 + v1*v1 + v2*v2 + v3*v3;
    #pragma unroll
    for (int o = 32; o >= 1; o >>= 1) { s += __shfl_xor(s, o); sq += __shfl_xor(sq, o); }
    const float mean = s * (1.0f / 256.0f);
    const float var  = sq * (1.0f / 256.0f) - mean * mean;
    const float rs = rsqrtf(var + 1e-5f);
    const float4 gv = *(const float4*)(g + lane * 4);
    const float4 bv = *(const float4*)(bta + lane * 4);
    bf16 ov[4] = { f2b((v0 - mean) * rs * gv.x + bv.x), f2b((v1 - mean) * rs * gv.y + bv.y),
                   f2b((v2 - mean) * rs * gv.z + bv.z), f2b((v3 - mean) * rs * gv.w + bv.w) };
    *(ushort4*)(valid + (size_t)node * 256 + lane * 4) = *(const ushort4*)ov;
}

// ---------------- confidence layer2 + weighted (wave per node) ----------------
__global__ __launch_bounds__(256) void conf_w_k(
    const bf16* __restrict__ t1, const float* __restrict__ Wc2, const float* __restrict__ bc2,
    const bf16* __restrict__ valid, float* __restrict__ conf, bf16* __restrict__ cat2)
{
    const int node = blockIdx.x * 4 + (threadIdx.x >> 6);
    const int lane = threadIdx.x & 63;
    float a = b2f(t1[(size_t)node * 128 + lane]) * Wc2[lane]
            + b2f(t1[(size_t)node * 128 + 64 + lane]) * Wc2[64 + lane];
    #pragma unroll
    for (int o = 32; o >= 1; o >>= 1) a += __shfl_xor(a, o);
    const float c = 1.0f / (1.0f + __expf(-(a + bc2[0])));
    if (lane == 0) conf[node] = c;
    const ushort4 vv = *(const ushort4*)(valid + (size_t)node * 256 + lane * 4);
    bf16 ov[4] = { f2b(us2f(vv.x) * c), f2b(us2f(vv.y) * c), f2b(us2f(vv.z) * c), f2b(us2f(vv.w) * c) };
    *(ushort4*)(cat2 + (size_t)node * 512 + 256 + lane * 4) = *(const ushort4*)ov;
}

// ---------------- CSR8 build: counts, hierarchical scan, fill ----------------
__global__ __launch_bounds__(256) void count8_k(
    const int* __restrict__ dst, const int* __restrict__ et, int* __restrict__ cnt8)
{
    const int e = blockIdx.x * 256 + threadIdx.x;
    if (e < E_) atomicAdd(&cnt8[dst[e] * 8 + et[e]], 1);
}

__global__ __launch_bounds__(256) void scanA_k(
    const int* __restrict__ cnt8, int* __restrict__ bsum)
{
    __shared__ int red[256];
    const int tid = threadIdx.x;
    red[tid] = cnt8[blockIdx.x * 256 + tid];
    __syncthreads();
    for (int s = 128; s > 0; s >>= 1) { if (tid < s) red[tid] += red[tid + s]; __syncthreads(); }
    if (tid == 0) bsum[blockIdx.x] = red[0];
}

__global__ __launch_bounds__(256) void scanB_k(
    const int* __restrict__ bsum, int* __restrict__ boff)
{
    __shared__ int part[256];
    const int tid = threadIdx.x;
    const int v0 = bsum[tid * 2], v1 = bsum[tid * 2 + 1];
    part[tid] = v0 + v1;
    __syncthreads();
    for (int off = 1; off < 256; off <<= 1) {
        int t = (tid >= off) ? part[tid - off] : 0;
        __syncthreads();
        part[tid] += t;
        __syncthreads();
    }
    const int base = (tid == 0) ? 0 : part[tid - 1];
    boff[tid * 2] = base;
    boff[tid * 2 + 1] = base + v0;
}

__global__ __launch_bounds__(256) void scanC_k(
    const int* __restrict__ cnt8, const int* __restrict__ boff,
    int* __restrict__ rowptr8, int* __restrict__ cursor8)
{
    __shared__ int part[256];
    const int tid = threadIdx.x;
    const int gbase = blockIdx.x * 256;
    const int v = cnt8[gbase + tid];
    part[tid] = v;
    __syncthreads();
    for (int off = 1; off < 256; off <<= 1) {
        int t = (tid >= off) ? part[tid - off] : 0;
        __syncthreads();
        part[tid] += t;
        __syncthreads();
    }
    const int excl = part[tid] - v + boff[blockIdx.x];
    rowptr8[gbase + tid] = excl;
    cursor8[gbase + tid] = excl;
    if (blockIdx.x == 511 && tid == 255) rowptr8[BN_ * 8] = excl + v;
}

__global__ __launch_bounds__(256) void fill8_k(
    const int* __restrict__ src, const int* __restrict__ dst, const int* __restrict__ et,
    int* __restrict__ cursor8, int* __restrict__ elist)
{
    const int e = blockIdx.x * 256 + threadIdx.x;
    if (e < E_) {
        const int pos = atomicAdd(&cursor8[dst[e] * 8 + et[e]], 1);
        elist[pos] = src[e];
    }
}

// ---------------- RGCN aggregate-first: S[node] = [mean_r xn rows (8x256) | xn row] ----------------
__global__ __launch_bounds__(256) void gather_sum_k(
    const int* __restrict__ rowptr8, const int* __restrict__ elist,
    const bf16* __restrict__ xn, bf16* __restrict__ S)
{
    const int node = blockIdx.x * 4 + (threadIdx.x >> 6);
    const int lane = threadIdx.x & 63;
    bf16* Srow = S + (size_t)node * 2304;
    *(ushort4*)(Srow + 2048 + lane * 4) = *(const ushort4*)(xn + (size_t)node * 256 + lane * 4);
    const int base = node * 8;
    #pragma unroll
    for (int r = 0; r < 8; ++r) {
        const int e0 = rowptr8[base + r], e1 = rowptr8[base + r + 1];
        float a0 = 0.f, a1 = 0.f, a2 = 0.f, a3 = 0.f;
        int e = e0;
        for (; e + 1 < e1; e += 2) {
            const int s0 = elist[e], s1 = elist[e + 1];
            const ushort4 h0 = *(const ushort4*)(xn + (size_t)s0 * 256 + lane * 4);
            const ushort4 h1 = *(const ushort4*)(xn + (size_t)s1 * 256 + lane * 4);
            a0 += us2f(h0.x) + us2f(h1.x);
            a1 += us2f(h0.y) + us2f(h1.y);
            a2 += us2f(h0.z) + us2f(h1.z);
            a3 += us2f(h0.w) + us2f(h1.w);
        }
        if (e < e1) {
            const ushort4 hv = *(const ushort4*)(xn + (size_t)elist[e] * 256 + lane * 4);
            a0 += us2f(hv.x); a1 += us2f(hv.y); a2 += us2f(hv.z); a3 += us2f(hv.w);
        }
        const float inv = 1.0f / fmaxf((float)(e1 - e0), 1.0f);
        bf16 ov[4] = { f2b(a0 * inv), f2b(a1 * inv), f2b(a2 * inv), f2b(a3 * inv) };
        *(ushort4*)(Srow + r * 256 + lane * 4) = *(const ushort4*)ov;
    }
}

// ---------------- pooling stage 1 ----------------
__global__ __launch_bounds__(256) void pool1_k(
    const bf16* __restrict__ xr, const float* __restrict__ conf, float* __restrict__ partial)
{
    const int b = blockIdx.x, chunk = blockIdx.y, c = threadIdx.x;
    float acc = 0.0f;
    for (int n = 0; n < 64; ++n) {
        const int node = b * 1024 + chunk * 64 + n;
        acc += conf[node] * b2f(xr[(size_t)node * 256 + c]);
    }
    partial[(size_t)(b * 16 + chunk) * 256 + c] = acc;
}

// ---------------- pooling stage 2 + head ----------------
__global__ __launch_bounds__(256) void pool2_k(
    const float* __restrict__ partial, const float* __restrict__ conf,
    const float* __restrict__ Wh, const float* __restrict__ bh, float* __restrict__ out)
{
    const int b = blockIdx.x, tid = threadIdx.x;
    __shared__ float red[256];
    __shared__ float pooled[256];
    float pc = 0.0f;
    for (int ch = 0; ch < 16; ++ch) pc += partial[(size_t)(b * 16 + ch) * 256 + tid];
    float s = conf[b * 1024 + tid] + conf[b * 1024 + 256 + tid]
            + conf[b * 1024 + 512 + tid] + conf[b * 1024 + 768 + tid];
    red[tid] = s; __syncthreads();
    for (int st = 128; st > 0; st >>= 1) { if (tid < st) red[tid] += red[tid + st]; __syncthreads(); }
    const float denom = fmaxf(red[0], 1e-8f);
    pooled[tid] = pc / denom;
    __syncthreads();
    if (tid < NS_) {
        float o = bh[tid];
        for (int c = 0; c < 256; ++c) o += pooled[c] * Wh[c * NS_ + tid];
        out[b * NS_ + tid] = o;
    }
}

extern "C" void kernel_launch(void* const* d_in, const int* in_sizes, int n_in,
                              void* d_out, int out_size, void* d_ws, size_t ws_size,
                              hipStream_t stream) {
    const float* x    = (const float*)d_in[0];
    const int*   ei   = (const int*)d_in[1];
    const int*   et   = (const int*)d_in[2];
    const float* Wq   = (const float*)d_in[3];  const float* bq  = (const float*)d_in[4];
    const float* Wk   = (const float*)d_in[5];  const float* bk  = (const float*)d_in[6];
    const float* Wv   = (const float*)d_in[7];  const float* bv  = (const float*)d_in[8];
    const float* Wg   = (const float*)d_in[9];  const float* bg  = (const float*)d_in[10];
    const float* lag  = (const float*)d_in[11]; const float* lab = (const float*)d_in[12];
    const float* Wc1  = (const float*)d_in[13]; const float* bc1 = (const float*)d_in[14];
    const float* Wc2  = (const float*)d_in[15]; const float* bc2 = (const float*)d_in[16];
    const float* Wm   = (const float*)d_in[17]; const float* bm  = (const float*)d_in[18];
    const float* l1g  = (const float*)d_in[19]; const float* l1b = (const float*)d_in[20];
    const float* Wrel = (const float*)d_in[21]; const float* Wroot = (const float*)d_in[22];
    const float* brg  = (const float*)d_in[23];
    const float* l2g  = (const float*)d_in[24]; const float* l2b = (const float*)d_in[25];
    const float* Wh   = (const float*)d_in[26]; const float* bh  = (const float*)d_in[27];
    const int* esrc = ei;
    const int* edst = ei + E_;

    char* w8 = (char*)d_ws;
    bf16*  qkv   = (bf16*)(w8 + 0);            // [16384,768]
    bf16*  Sbig  = (bf16*)(w8 + 0);            // [16384,2304] 75.5 MB (qkv/sP/cat1 dead by then)
    bf16*  sP    = (bf16*)(w8 + 25165824);     // [16x1024x1024]
    bf16*  cat1  = (bf16*)(w8 + 58720256);     // [aout|xb] ld 512
    bf16*  cat2  = (bf16*)(w8 + 75497472);     // [xb|weighted] ld 512; reused as pk0 after mixer
    bf16*  gate  = (bf16*)(w8 + 92274688);     // 8 MB; gate+valid reused as pk1 after conf_w
    bf16*  valid = (bf16*)(w8 + 100663296);
    bf16*  t1    = (bf16*)(w8 + 109051904);
    bf16*  xm    = (bf16*)(w8 + 113246208);
    bf16*  xb    = (bf16*)(w8 + 121634816);
    bf16*  xn    = (bf16*)(w8 + 130023424);
    bf16*  vtb   = (bf16*)(w8 + 138412032);
    bf16*  xr    = (bf16*)(w8 + 146800640);
    float* conf  = (float*)(w8 + 155189248);
    float* part  = (float*)(w8 + 155254784);
    bf16*  WT    = (bf16*)(w8 + 155516928);    // 2,162,688 B -> ends 157,679,616
    int*  cnt8i   = (int*)(w8 + 157679616);    // 524,288 B
    int*  rowptr8 = (int*)(w8 + 158203904);    // 524,292 B (+pad)
    int*  cursor8 = (int*)(w8 + 158728448);    // 524,288 B
    int*  elist   = (int*)(w8 + 159252736);    // 1,048,576 B
    int*  bsum    = (int*)(w8 + 160301312);    // 2,048 B
    int*  boff    = (int*)(w8 + 160303360);    // 2,048 B
    bf16* WqkvT = WT;                  // [768,256]
    bf16* WgT   = WT + 196608;         // [256,512]
    bf16* WmT   = WT + 327680;         // [256,512]
    bf16* Wc1T  = WT + 458752;         // [128,256]
    bf16* WB2   = WT + 491520;         // [256,2304]
    float* pk0  = (float*)cat2;        // 16 MB fp32 partial (cat2 dead after mixer)
    float* pk1  = (float*)gate;        // 16 MB fp32 partial (gate+valid dead after conf_w)
    float* outp = (float*)d_out;

    dim3 blk(256);

    // --- prep: weights, x conversion, CSR8 build (hierarchical scan) ---
    prep_w_k<<<1056, blk, 0, stream>>>(Wq, Wk, Wv, Wg, Wm, Wc1, Wrel, Wroot, WT);
    cvt_x_k<<<BNC_ / 1024, blk, 0, stream>>>(x, xb, cat1, cat2);
    hipMemsetAsync(cnt8i, 0, (size_t)BN_ * 8 * sizeof(int), stream);
    count8_k<<<E_ / 256, blk, 0, stream>>>(edst, et, cnt8i);
    scanA_k<<<512, blk, 0, stream>>>(cnt8i, bsum);
    scanB_k<<<1, blk, 0, stream>>>(bsum, boff);
    scanC_k<<<512, blk, 0, stream>>>(cnt8i, boff, rowptr8, cursor8);
    fill8_k<<<E_ / 256, blk, 0, stream>>>(esrc, edst, et, cursor8, elist);

    // --- fused QKV projection: qkv[16384,768] ---
    gemm_bf16<0><<<dim3(6, 128, 1), blk, 0, stream>>>(
        xb, 256, 0, WqkvT, 256, 0, qkv, 768, 0, bq, bk, bv, 256);
    vtrans_k<<<dim3(8, 32, 16), blk, 0, stream>>>(qkv, vtb);

    // --- attention: QK^T (64-tile depth-4), softmax, PV (128-tile) ---
    gemm64_bf16<0><<<dim3(16, 16, 16), blk, 0, stream>>>(
        qkv, 768, 786432, qkv + 256, 768, 786432, sP, 1024, 1048576, nullptr, 256);
    softmax_k<<<BN_, blk, 0, stream>>>(sP);
    gemm_bf16<0><<<dim3(2, 8, 16), blk, 0, stream>>>(
        sP, 1024, 1048576, vtb, 1024, 262144, cat1, 512, 524288, nullptr, nullptr, nullptr, 1024);

    // --- gate (64-tile depth-4), blend+LN ---
    gemm64_bf16<2><<<dim3(4, 256, 1), blk, 0, stream>>>(
        cat1, 512, 0, WgT, 512, 0, gate, 256, 0, bg, 512);
    blend_ln_k<<<BN_ / 4, blk, 0, stream>>>(gate, cat1, xb, valid, lag, lab);

    // --- confidence (64-tile depth-4) + weighted ---
    gemm64_bf16<1><<<dim3(2, 256, 1), blk, 0, stream>>>(
        valid, 256, 0, Wc1T, 256, 0, t1, 128, 0, bc1, 256);
    conf_w_k<<<BN_ / 4, blk, 0, stream>>>(t1, Wc2, bc2, valid, conf, cat2);

    // --- mixer (64-tile depth-4) + LN1 ---
    gemm64_bf16<1><<<dim3(4, 256, 1), blk, 0, stream>>>(
        cat2, 512, 0, WmT, 512, 0, xm, 256, 0, bm, 512);
    ln_k<0><<<BN_ / 4, blk, 0, stream>>>(xm, xn, l1g, l1b);

    // --- RGCN aggregate-first: gather-mean, split-K=2 GEMM (fp32 partials), reduce+LN ---
    gather_sum_k<<<BN_ / 4, blk, 0, stream>>>(rowptr8, elist, xn, Sbig);
    gemm_splitk<<<dim3(2, 128, 2), blk, 0, stream>>>(
        Sbig, 2304, WB2, 2304, pk0, 1152);
    redln_k<<<BN_ / 4, blk, 0, stream>>>(pk0, pk1, brg, l2g, l2b, xr);

    // --- pool + head ---
    pool1_k<<<dim3(B_, 16), blk, 0, stream>>>(xr, conf, part);
    pool2_k<<<B_, blk, 0, stream>>>(part, conf, Wh, bh, outp);
}